// Round 11
// baseline (1320.617 us; speedup 1.0000x reference)
//
#include <hip/hip_runtime.h>
#include <hip/hip_bf16.h>
#include <math.h>

#define B_ 8
#define H_ 8
#define T_ 8192
#define D_ 64
#define NC_ 128
#define WSZ_ 64
#define T2_ (2*T_)
#define BH_ (B_*H_)

// workspace layout (bytes)
#define OFF_AUX    0
#define OFF_DEN    4096                              // den, BH*T*4
#define OFF_QIDX   (OFF_DEN  + BH_*T_*4)
#define OFF_KIDX   (OFF_QIDX + BH_*NC_*WSZ_*4)
#define OFF_MEANST (OFF_KIDX + BH_*NC_*WSZ_*4)
#define OFF_DISTS  (OFF_MEANST + H_*NC_*D_*4)
// dists region: nbh*NC_*T2_*4 bytes (8 MB per bh)

// ---------------------------------------------------------------------------
// K0: transpose means [h][c][d] -> meanst [h][d][c]
// ---------------------------------------------------------------------------
__global__ __launch_bounds__(256)
void k_meanst(const float* __restrict__ means, float* __restrict__ meanst)
{
    int gid = blockIdx.x * 256 + threadIdx.x;
    int h = gid >> 13;
    int rem = gid & 8191;
    int d = rem >> 7;
    int c = rem & 127;
    meanst[gid] = means[((h << 7) | c) * 64 + d];
}

// ---------------------------------------------------------------------------
// K1 v6: r5 structure + double-buffered means register prefetch, NO min-waves
// bound (r7 lesson: the (256,4) cap — not the prefetch — caused the spill;
// natural demand ~120 VGPR still allows 4 waves/SIMD). FMA order per acc
// element ascending-d -> bitwise-identical dists vs all passing rounds.
// grid: (T2/128, nbh)  block: 256
// ---------------------------------------------------------------------------
__global__ __launch_bounds__(256)
void k_dists(const float* __restrict__ q, const float* __restrict__ k,
             const float* __restrict__ means, const float* __restrict__ meanst,
             float* __restrict__ dists, float* __restrict__ aux, int bh_base)
{
    __shared__ float xs[64 * 132];   // [d][token], stride 132
    __shared__ int   bcs[128];
    __shared__ float ar[4];

    const int tid = threadIdx.x;
    const int bhl = blockIdx.y;
    const int bh  = bh_base + bhl;
    const int h   = bh % H_;
    const int t0  = blockIdx.x * 128;

    // ---- phase 1: load 128 token rows (nt), normalize, store transposed
    const int lane = tid & 63;
    const int w    = tid >> 6;
    for (int it = 0; it < 32; ++it) {
        int tl = it * 4 + w;
        int gt = t0 + tl;
        const float* src = (gt < T_)
            ? (q + ((size_t)bh * T_ + gt) * D_)
            : (k + ((size_t)bh * T_ + (gt - T_)) * D_);
        float vv = __builtin_nontemporal_load(src + lane);
        float s = vv * vv;
        #pragma unroll
        for (int off = 32; off > 0; off >>= 1) s += __shfl_xor(s, off);
        float norm = fmaxf(sqrtf(s), 1e-12f);
        xs[lane * 132 + tl] = vv / norm;
    }
    __syncthreads();

    // ---- phase 2: 8x8 tile per thread over d, means double-buffer prefetch
    const int ty = tid >> 4;     // token group
    const int tx = tid & 15;     // cluster group
    float acc[8][8];
    #pragma unroll
    for (int i = 0; i < 8; ++i)
        #pragma unroll
        for (int j = 0; j < 8; ++j) acc[i][j] = 0.f;

    const float* mt = meanst + (size_t)h * (64 * 128) + tx * 8;

    float4 mA0, mA1, mA2, mA3, mB0, mB1, mB2, mB3;
    // preload group 0 (d=0,1)
    mA0 = *(const float4*)(mt + 0);
    mA1 = *(const float4*)(mt + 4);
    mA2 = *(const float4*)(mt + 128);
    mA3 = *(const float4*)(mt + 132);

#define CDOT(dd, M0, M1) { \
    float4 xa_ = *(const float4*)&xs[(dd) * 132 + ty * 8]; \
    float4 xb_ = *(const float4*)&xs[(dd) * 132 + ty * 8 + 4]; \
    float xv_[8] = {xa_.x, xa_.y, xa_.z, xa_.w, xb_.x, xb_.y, xb_.z, xb_.w}; \
    float mv_[8] = {M0.x, M0.y, M0.z, M0.w, M1.x, M1.y, M1.z, M1.w}; \
    _Pragma("unroll") \
    for (int i_ = 0; i_ < 8; ++i_) \
        _Pragma("unroll") \
        for (int j_ = 0; j_ < 8; ++j_) \
            acc[i_][j_] = fmaf(xv_[i_], mv_[j_], acc[i_][j_]); }

    for (int g = 0; g < 32; g += 2) {
        {
            int gn = (g + 1 < 32) ? g + 1 : 31;
            const float* p = mt + gn * 256;
            mB0 = *(const float4*)(p + 0);
            mB1 = *(const float4*)(p + 4);
            mB2 = *(const float4*)(p + 128);
            mB3 = *(const float4*)(p + 132);
        }
        CDOT(2 * g,     mA0, mA1);
        CDOT(2 * g + 1, mA2, mA3);
        {
            int gn = (g + 2 < 32) ? g + 2 : 31;
            const float* p = mt + gn * 256;
            mA0 = *(const float4*)(p + 0);
            mA1 = *(const float4*)(p + 4);
            mA2 = *(const float4*)(p + 128);
            mA3 = *(const float4*)(p + 132);
        }
        CDOT(2 * g + 2, mB0, mB1);
        CDOT(2 * g + 3, mB2, mB3);
    }
#undef CDOT

    // ---- phase 3: direct transposed global store
    #pragma unroll
    for (int j = 0; j < 8; ++j) {
        const int c = tx * 8 + j;
        float* gp = dists + ((size_t)(bhl * NC_ + c)) * T2_ + t0 + ty * 8;
        *(float4*)gp       = make_float4(acc[0][j], acc[1][j], acc[2][j], acc[3][j]);
        *(float4*)(gp + 4) = make_float4(acc[4][j], acc[5][j], acc[6][j], acc[7][j]);
    }

    // ---- phase 4: argmax across clusters (16-lane groups share tokens)
    #pragma unroll
    for (int i = 0; i < 8; ++i) {
        float bv = -1e30f; int bcid = 0;
        #pragma unroll
        for (int j = 0; j < 8; ++j) {
            float vv = acc[i][j];
            if (vv > bv) { bv = vv; bcid = tx * 8 + j; }
        }
        #pragma unroll
        for (int off = 1; off < 16; off <<= 1) {
            float ov = __shfl_xor(bv, off);
            int   oc = __shfl_xor(bcid, off);
            if (ov > bv || (ov == bv && oc < bcid)) { bv = ov; bcid = oc; }
        }
        if (tx == 0) bcs[ty * 8 + i] = bcid;
    }
    __syncthreads();

    // ---- phase 5: aux = sum (xn - mean_best)^2
    float part = 0.f;
    for (int it = 0; it < 32; ++it) {
        int tl = it * 4 + w;
        int cb = bcs[tl];
        const float* mr = means + ((size_t)(h * NC_ + cb)) * 64;
        float df = xs[lane * 132 + tl] - mr[lane];
        part = fmaf(df, df, part);
    }
    #pragma unroll
    for (int off = 32; off > 0; off >>= 1) part += __shfl_xor(part, off);
    if (lane == 0) ar[w] = part;
    __syncthreads();
    if (tid == 0) atomicAdd(aux, ar[0] + ar[1] + ar[2] + ar[3]);
}

// ---------------------------------------------------------------------------
// K2: top-64 of 8192 — register-resident, 12-bit histogram, parallel
// suffix-scan threshold, exact candidate rank.  (unchanged, passing)
// ---------------------------------------------------------------------------
__device__ __forceinline__ unsigned flip_f32(float f) {
    unsigned bits = __float_as_uint(f);
    return (bits & 0x80000000u) ? ~bits : (bits | 0x80000000u);
}

__global__ __launch_bounds__(256)
void k_topk(const float* __restrict__ dists, int* __restrict__ qidx,
            int* __restrict__ kidx, int bh_base)
{
    __shared__ unsigned hist[4096];
    __shared__ unsigned sfx[256];
    __shared__ unsigned wtot[4];
    __shared__ unsigned cand_u[768];
    __shared__ int      cand_i[768];
    __shared__ int sh[6];

    const int tid   = threadIdx.x;
    const int c     = blockIdx.x;
    const int bhl   = blockIdx.y;
    const int which = blockIdx.z;
    const float* row = dists + ((size_t)(bhl * NC_ + c)) * T2_ + (size_t)which * T_;
    int* outp = (which ? kidx : qidx) + ((size_t)((bh_base + bhl) * NC_ + c)) * WSZ_;

    unsigned u[32];
    {
        const float4* r4 = (const float4*)row;
        #pragma unroll
        for (int it = 0; it < 8; ++it) {
            float4 f = r4[it * 256 + tid];
            u[it * 4 + 0] = flip_f32(f.x);
            u[it * 4 + 1] = flip_f32(f.y);
            u[it * 4 + 2] = flip_f32(f.z);
            u[it * 4 + 3] = flip_f32(f.w);
        }
    }
    for (int i = tid; i < 4096; i += 256) hist[i] = 0;
    if (tid < 6) sh[tid] = (tid < 2) ? -1 : 0;
    __syncthreads();

    #pragma unroll
    for (int j = 0; j < 32; ++j) atomicAdd(&hist[u[j] >> 20], 1u);
    __syncthreads();

    unsigned gs = 0;
    #pragma unroll
    for (int j = 0; j < 16; ++j) gs += hist[tid * 16 + j];

    const int l = tid & 63, w = tid >> 6;
    unsigned sv = gs;
    #pragma unroll
    for (int off = 1; off < 64; off <<= 1) {
        unsigned up = __shfl_down(sv, off);
        if (l + off < 64) sv += up;
    }
    if (l == 0) wtot[w] = sv;
    __syncthreads();
    unsigned hi = 0;
    for (int ww = w + 1; ww < 4; ++ww) hi += wtot[ww];
    unsigned suffix = sv + hi;
    sfx[tid] = suffix;
    if (suffix >= WSZ_) atomicMax(&sh[0], tid);
    __syncthreads();
    const int g1 = sh[0];
    const unsigned above_groups = (g1 < 255) ? sfx[g1 + 1] : 0u;

    if (tid < 16) {
        unsigned bs = above_groups;
        for (int j = 15; j >= tid; --j) bs += hist[g1 * 16 + j];
        if (bs >= WSZ_) atomicMax(&sh[1], g1 * 16 + tid);
    }
    __syncthreads();
    const int b1 = sh[1];
    if (tid == 0) {
        unsigned gt = above_groups;
        for (int j = b1 + 1; j <= g1 * 16 + 15; ++j) gt += hist[j];
        sh[4] = WSZ_ - (int)gt;
    }
    __syncthreads();
    const int kk = sh[4];

    #pragma unroll
    for (int j = 0; j < 32; ++j) {
        int bin = (int)(u[j] >> 20);
        int idx = (j >> 2) * 1024 + tid * 4 + (j & 3);
        if (bin > b1) {
            int p = atomicAdd(&sh[2], 1);
            outp[p] = idx;
        } else if (bin == b1) {
            int p = atomicAdd(&sh[3], 1);
            if (p < 768) { cand_u[p] = u[j]; cand_i[p] = idx; }
        }
    }
    __syncthreads();
    const int G = sh[2];
    const int C = sh[3];

    if (C <= 768) {
        for (int j = tid; j < C; j += 256) {
            unsigned uj = cand_u[j]; int ij = cand_i[j];
            int rank = 0;
            for (int ll = 0; ll < C; ++ll) {
                unsigned ul = cand_u[ll];
                rank += (int)((ul > uj) || (ul == uj && cand_i[ll] < ij));
            }
            if (rank < kk) outp[G + rank] = ij;
        }
        return;
    }

    // fallback: full 4-level radix re-reading global
    unsigned prefix = 0, mask = 0;
    int need = WSZ_;
    for (int shift = 24; shift >= 0; shift -= 8) {
        if (tid < 256) hist[tid] = 0;
        __syncthreads();
        for (int it = 0; it < 32; ++it) {
            unsigned uu = flip_f32(row[it * 256 + tid]);
            if ((uu & mask) == prefix) atomicAdd(&hist[(uu >> shift) & 255u], 1u);
        }
        __syncthreads();
        if (tid == 0) {
            int b = 255;
            int k2 = need;
            while (b > 0) {
                int cnt = (int)hist[b];
                if (k2 - cnt <= 0) break;
                k2 -= cnt; --b;
            }
            sh[0] = k2; sh[1] = b;
        }
        __syncthreads();
        need = sh[0];
        prefix |= ((unsigned)sh[1]) << shift;
        mask   |= 0xFFu << shift;
        __syncthreads();
    }
    if (tid == 0) { sh[2] = 0; sh[3] = 0; }
    __syncthreads();
    const unsigned thr = prefix;
    for (int it = 0; it < 32; ++it) {
        int i = it * 256 + tid;
        unsigned uu = flip_f32(row[i]);
        if (uu > thr) {
            int p = atomicAdd(&sh[2], 1);
            outp[p] = i;
        } else if (uu == thr) {
            int p = atomicAdd(&sh[3], 1);
            if (p < 768) cand_i[p] = i;
        }
    }
    __syncthreads();
    if (tid == 0) {
        int base = sh[2];
        int E = sh[3] < 768 ? sh[3] : 768;
        for (int n = 0; n < need; ++n) {
            int mi = 0x7fffffff, mj = 0;
            for (int j = 0; j < E; ++j) {
                int vv = cand_i[j];
                if (vv < mi) { mi = vv; mj = j; }
            }
            cand_i[mj] = 0x7fffffff;
            outp[base + n] = mi;
        }
    }
}

// ---------------------------------------------------------------------------
// K3 v6: atomic-scatter attention + V-prefetch + STRIDED key assignment in
// QK^T (thread tx owns keys {tx, tx+16, tx+32, tx+48}): lane stride becomes
// 68 floats -> 4*tx mod 32 banks -> 2-way (free), vs 8-way for tx*4+j.
// P stored at column (tx+16j) so As[row][col]=P[row][col]; PV loop unchanged.
// grid: (NC, BH)  block: 256
// ---------------------------------------------------------------------------
__global__ __launch_bounds__(256)
void k_attn(const float* __restrict__ q, const float* __restrict__ k,
            const float* __restrict__ v, const int* __restrict__ qidx,
            const int* __restrict__ kidx, float* __restrict__ out,
            float* __restrict__ den)
{
    __shared__ float As[64 * 68];   // Q, then P
    __shared__ float Bs[64 * 68];   // K, then V
    __shared__ int qi[64], ki[64];

    const int tid = threadIdx.x;
    const int c  = blockIdx.x;
    const int bh = blockIdx.y;
    const int* qp = qidx + ((size_t)(bh * NC_ + c)) * WSZ_;
    const int* kp = kidx + ((size_t)(bh * NC_ + c)) * WSZ_;
    if (tid < 64) { qi[tid] = qp[tid]; ki[tid] = kp[tid]; }
    __syncthreads();

    const int grow = tid >> 2, gseg = (tid & 3) * 16;
    {
        const float* qsrc = q + ((size_t)bh * T_ + qi[grow]) * D_ + gseg;
        const float* ksrc = k + ((size_t)bh * T_ + ki[grow]) * D_ + gseg;
        #pragma unroll
        for (int j4 = 0; j4 < 4; ++j4) {
            *(float4*)&As[grow * 68 + gseg + j4 * 4] = ((const float4*)qsrc)[j4];
            *(float4*)&Bs[grow * 68 + gseg + j4 * 4] = ((const float4*)ksrc)[j4];
        }
    }

    // issue V gather early (registers) — latency hides under QK^T
    float4 vr0, vr1, vr2, vr3;
    {
        const float4* vsrc = (const float4*)(v + ((size_t)bh * T_ + ki[grow]) * D_ + gseg);
        vr0 = vsrc[0]; vr1 = vsrc[1]; vr2 = vsrc[2]; vr3 = vsrc[3];
    }
    __syncthreads();

    const int tx = tid & 15;
    const int ty = tid >> 4;

    // sacc[i][j] = score(row ty*4+i, key tx + 16*j)
    float sacc[4][4];
    #pragma unroll
    for (int i = 0; i < 4; ++i)
        #pragma unroll
        for (int j = 0; j < 4; ++j) sacc[i][j] = 0.f;

    for (int kk4 = 0; kk4 < 16; ++kk4) {
        float4 qv[4], kv[4];
        #pragma unroll
        for (int i = 0; i < 4; ++i) qv[i] = *(const float4*)&As[(ty * 4 + i) * 68 + kk4 * 4];
        #pragma unroll
        for (int j = 0; j < 4; ++j) kv[j] = *(const float4*)&Bs[(tx + j * 16) * 68 + kk4 * 4];
        #pragma unroll
        for (int i = 0; i < 4; ++i)
            #pragma unroll
            for (int j = 0; j < 4; ++j)
                sacc[i][j] = fmaf(qv[i].w, kv[j].w, fmaf(qv[i].z, kv[j].z,
                              fmaf(qv[i].y, kv[j].y, fmaf(qv[i].x, kv[j].x, sacc[i][j]))));
    }
    __syncthreads();   // K reads done -> Bs reusable

    {
        *(float4*)&Bs[grow * 68 + gseg +  0] = vr0;
        *(float4*)&Bs[grow * 68 + gseg +  4] = vr1;
        *(float4*)&Bs[grow * 68 + gseg +  8] = vr2;
        *(float4*)&Bs[grow * 68 + gseg + 12] = vr3;
    }

    float rinv[4];
    #pragma unroll
    for (int i = 0; i < 4; ++i) {
        float m = fmaxf(fmaxf(sacc[i][0], sacc[i][1]), fmaxf(sacc[i][2], sacc[i][3]));
        m = fmaxf(m, __shfl_xor(m, 1));
        m = fmaxf(m, __shfl_xor(m, 2));
        m = fmaxf(m, __shfl_xor(m, 4));
        m = fmaxf(m, __shfl_xor(m, 8));
        float4 ev;
        ev.x = expf((sacc[i][0] - m) * 0.125f);
        ev.y = expf((sacc[i][1] - m) * 0.125f);
        ev.z = expf((sacc[i][2] - m) * 0.125f);
        ev.w = expf((sacc[i][3] - m) * 0.125f);
        float s = ev.x + ev.y + ev.z + ev.w;
        s += __shfl_xor(s, 1);
        s += __shfl_xor(s, 2);
        s += __shfl_xor(s, 4);
        s += __shfl_xor(s, 8);
        rinv[i] = 1.0f / s;
        const int rb = (ty * 4 + i) * 68 + tx;
        As[rb     ] = ev.x;
        As[rb + 16] = ev.y;
        As[rb + 32] = ev.z;
        As[rb + 48] = ev.w;
    }
    __syncthreads();

    float oacc[4][4];
    #pragma unroll
    for (int i = 0; i < 4; ++i)
        #pragma unroll
        for (int j = 0; j < 4; ++j) oacc[i][j] = 0.f;

    for (int jj4 = 0; jj4 < 16; ++jj4) {
        float4 vv[4];
        #pragma unroll
        for (int ll = 0; ll < 4; ++ll) vv[ll] = *(const float4*)&Bs[(jj4 * 4 + ll) * 68 + tx * 4];
        #pragma unroll
        for (int i = 0; i < 4; ++i) {
            float4 pv = *(const float4*)&As[(ty * 4 + i) * 68 + jj4 * 4];
            oacc[i][0] = fmaf(pv.w, vv[3].x, fmaf(pv.z, vv[2].x, fmaf(pv.y, vv[1].x, fmaf(pv.x, vv[0].x, oacc[i][0]))));
            oacc[i][1] = fmaf(pv.w, vv[3].y, fmaf(pv.z, vv[2].y, fmaf(pv.y, vv[1].y, fmaf(pv.x, vv[0].y, oacc[i][1]))));
            oacc[i][2] = fmaf(pv.w, vv[3].z, fmaf(pv.z, vv[2].z, fmaf(pv.y, vv[1].z, fmaf(pv.x, vv[0].z, oacc[i][2]))));
            oacc[i][3] = fmaf(pv.w, vv[3].w, fmaf(pv.z, vv[2].w, fmaf(pv.y, vv[1].w, fmaf(pv.x, vv[0].w, oacc[i][3]))));
        }
    }

    #pragma unroll
    for (int i = 0; i < 4; ++i) {
        const int r = ty * 4 + i;
        float* obase = out + ((size_t)bh * T_ + qi[r]) * D_ + tx * 4;
        #pragma unroll
        for (int j = 0; j < 4; ++j) atomicAdd(obase + j, oacc[i][j] * rinv[i]);
    }
    if (tx == 0) {
        #pragma unroll
        for (int i = 0; i < 4; ++i) atomicAdd(den + (size_t)bh * T_ + qi[ty * 4 + i], 1.0f);
    }
}

// ---------------------------------------------------------------------------
// K4: out = num / (den + EPS); write aux
// ---------------------------------------------------------------------------
__global__ __launch_bounds__(256)
void k_final(float* __restrict__ out, const float* __restrict__ den,
             const float* __restrict__ aux)
{
    size_t gid = (size_t)blockIdx.x * 256 + threadIdx.x;
    float4* o4 = (float4*)out;
    float d = den[gid >> 4] + 1e-5f;
    float4 x = o4[gid];
    x.x = x.x / d; x.y = x.y / d; x.z = x.z / d; x.w = x.w / d;
    o4[gid] = x;
    if (gid == 0) out[(size_t)BH_ * T_ * D_] = aux[0] * 1.4901161193847656e-12f;
}

extern "C" void kernel_launch(void* const* d_in, const int* in_sizes, int n_in,
                              void* d_out, int out_size, void* d_ws, size_t ws_size,
                              hipStream_t stream) {
    const float* q     = (const float*)d_in[0];
    const float* k     = (const float*)d_in[1];
    const float* v     = (const float*)d_in[2];
    const float* means = (const float*)d_in[3];
    float* out = (float*)d_out;
    char*  ws  = (char*)d_ws;
    float* aux    = (float*)(ws + OFF_AUX);
    float* den    = (float*)(ws + OFF_DEN);
    int*   qidx   = (int*)(ws + OFF_QIDX);
    int*   kidx   = (int*)(ws + OFF_KIDX);
    float* meanst = (float*)(ws + OFF_MEANST);
    float* dists  = (float*)(ws + OFF_DISTS);

    hipMemsetAsync(out, 0, (size_t)((size_t)BH_ * T_ * D_ + 1) * 4, stream);
    hipMemsetAsync(ws, 0, (size_t)OFF_QIDX, stream);   // aux + den

    k_meanst<<<256, 256, 0, stream>>>(means, meanst);

    size_t region = (ws_size > OFF_DISTS) ? ws_size - (size_t)OFF_DISTS : 0;
    size_t per_bh = (size_t)NC_ * T2_ * 4;   // 8 MB
    int nbh = (int)(region / per_bh);
    nbh = nbh < 1 ? 1 : (nbh > BH_ ? BH_ : nbh);

    for (int bh_base = 0; bh_base < BH_; bh_base += nbh) {
        int cur = BH_ - bh_base < nbh ? BH_ - bh_base : nbh;
        k_dists<<<dim3(T2_ / 128, cur), 256, 0, stream>>>(q, k, means, meanst, dists, aux, bh_base);
        k_topk <<<dim3(NC_, cur, 2),    256, 0, stream>>>(dists, qidx, kidx, bh_base);
    }

    k_attn<<<dim3(NC_, BH_), 256, 0, stream>>>(q, k, v, qidx, kidx, out, den);
    k_final<<<(BH_ * T_ * D_ / 4 + 255) / 256, 256, 0, stream>>>(out, den, aux);
}

// Round 12
// 1294.392 us; speedup vs baseline: 1.0203x; 1.0203x over previous
//
#include <hip/hip_runtime.h>
#include <hip/hip_bf16.h>
#include <hip/hip_fp16.h>
#include <math.h>

#define B_ 8
#define H_ 8
#define T_ 8192
#define D_ 64
#define NC_ 128
#define WSZ_ 64
#define T2_ (2*T_)
#define BH_ (B_*H_)
#define SA 72   // k_attn LDS row stride in halves (144B: 16B-aligned rows, 2-way banks)

// workspace layout (bytes)
#define OFF_AUX    0
#define OFF_DEN    4096                              // den, BH*T*4
#define OFF_QIDX   (OFF_DEN  + BH_*T_*4)
#define OFF_KIDX   (OFF_QIDX + BH_*NC_*WSZ_*4)
#define OFF_MEANST (OFF_KIDX + BH_*NC_*WSZ_*4)
#define OFF_DISTS  (OFF_MEANST + H_*NC_*D_*4)
// dists region: nbh*NC_*T2_*4 bytes (8 MB per bh)

__device__ __forceinline__ float2 h2f(unsigned u) {
    __half2 h = *reinterpret_cast<__half2*>(&u);
    return __half22float2(h);
}
__device__ __forceinline__ unsigned f2h2(float a, float b) {
    __half2 h = __float22half2_rn(make_float2(a, b));
    return *reinterpret_cast<unsigned*>(&h);
}

// ---------------------------------------------------------------------------
// K0: transpose means [h][c][d] -> meanst [h][d][c]
// ---------------------------------------------------------------------------
__global__ __launch_bounds__(256)
void k_meanst(const float* __restrict__ means, float* __restrict__ meanst)
{
    int gid = blockIdx.x * 256 + threadIdx.x;
    int h = gid >> 13;
    int rem = gid & 8191;
    int d = rem >> 7;
    int c = rem & 127;
    meanst[gid] = means[((h << 7) | c) * 64 + d];
}

// ---------------------------------------------------------------------------
// K1 (r11, passing): dists + argmax + aux, 8tok x 8clu register tile with
// unbounded means double-buffer prefetch. Bitwise-identical dists.
// grid: (T2/128, nbh)  block: 256
// ---------------------------------------------------------------------------
__global__ __launch_bounds__(256)
void k_dists(const float* __restrict__ q, const float* __restrict__ k,
             const float* __restrict__ means, const float* __restrict__ meanst,
             float* __restrict__ dists, float* __restrict__ aux, int bh_base)
{
    __shared__ float xs[64 * 132];   // [d][token], stride 132
    __shared__ int   bcs[128];
    __shared__ float ar[4];

    const int tid = threadIdx.x;
    const int bhl = blockIdx.y;
    const int bh  = bh_base + bhl;
    const int h   = bh % H_;
    const int t0  = blockIdx.x * 128;

    const int lane = tid & 63;
    const int w    = tid >> 6;
    for (int it = 0; it < 32; ++it) {
        int tl = it * 4 + w;
        int gt = t0 + tl;
        const float* src = (gt < T_)
            ? (q + ((size_t)bh * T_ + gt) * D_)
            : (k + ((size_t)bh * T_ + (gt - T_)) * D_);
        float vv = __builtin_nontemporal_load(src + lane);
        float s = vv * vv;
        #pragma unroll
        for (int off = 32; off > 0; off >>= 1) s += __shfl_xor(s, off);
        float norm = fmaxf(sqrtf(s), 1e-12f);
        xs[lane * 132 + tl] = vv / norm;
    }
    __syncthreads();

    const int ty = tid >> 4;
    const int tx = tid & 15;
    float acc[8][8];
    #pragma unroll
    for (int i = 0; i < 8; ++i)
        #pragma unroll
        for (int j = 0; j < 8; ++j) acc[i][j] = 0.f;

    const float* mt = meanst + (size_t)h * (64 * 128) + tx * 8;

    float4 mA0, mA1, mA2, mA3, mB0, mB1, mB2, mB3;
    mA0 = *(const float4*)(mt + 0);
    mA1 = *(const float4*)(mt + 4);
    mA2 = *(const float4*)(mt + 128);
    mA3 = *(const float4*)(mt + 132);

#define CDOT(dd, M0, M1) { \
    float4 xa_ = *(const float4*)&xs[(dd) * 132 + ty * 8]; \
    float4 xb_ = *(const float4*)&xs[(dd) * 132 + ty * 8 + 4]; \
    float xv_[8] = {xa_.x, xa_.y, xa_.z, xa_.w, xb_.x, xb_.y, xb_.z, xb_.w}; \
    float mv_[8] = {M0.x, M0.y, M0.z, M0.w, M1.x, M1.y, M1.z, M1.w}; \
    _Pragma("unroll") \
    for (int i_ = 0; i_ < 8; ++i_) \
        _Pragma("unroll") \
        for (int j_ = 0; j_ < 8; ++j_) \
            acc[i_][j_] = fmaf(xv_[i_], mv_[j_], acc[i_][j_]); }

    for (int g = 0; g < 32; g += 2) {
        {
            int gn = (g + 1 < 32) ? g + 1 : 31;
            const float* p = mt + gn * 256;
            mB0 = *(const float4*)(p + 0);
            mB1 = *(const float4*)(p + 4);
            mB2 = *(const float4*)(p + 128);
            mB3 = *(const float4*)(p + 132);
        }
        CDOT(2 * g,     mA0, mA1);
        CDOT(2 * g + 1, mA2, mA3);
        {
            int gn = (g + 2 < 32) ? g + 2 : 31;
            const float* p = mt + gn * 256;
            mA0 = *(const float4*)(p + 0);
            mA1 = *(const float4*)(p + 4);
            mA2 = *(const float4*)(p + 128);
            mA3 = *(const float4*)(p + 132);
        }
        CDOT(2 * g + 2, mB0, mB1);
        CDOT(2 * g + 3, mB2, mB3);
    }
#undef CDOT

    #pragma unroll
    for (int j = 0; j < 8; ++j) {
        const int c = tx * 8 + j;
        float* gp = dists + ((size_t)(bhl * NC_ + c)) * T2_ + t0 + ty * 8;
        *(float4*)gp       = make_float4(acc[0][j], acc[1][j], acc[2][j], acc[3][j]);
        *(float4*)(gp + 4) = make_float4(acc[4][j], acc[5][j], acc[6][j], acc[7][j]);
    }

    #pragma unroll
    for (int i = 0; i < 8; ++i) {
        float bv = -1e30f; int bcid = 0;
        #pragma unroll
        for (int j = 0; j < 8; ++j) {
            float vv = acc[i][j];
            if (vv > bv) { bv = vv; bcid = tx * 8 + j; }
        }
        #pragma unroll
        for (int off = 1; off < 16; off <<= 1) {
            float ov = __shfl_xor(bv, off);
            int   oc = __shfl_xor(bcid, off);
            if (ov > bv || (ov == bv && oc < bcid)) { bv = ov; bcid = oc; }
        }
        if (tx == 0) bcs[ty * 8 + i] = bcid;
    }
    __syncthreads();

    float part = 0.f;
    for (int it = 0; it < 32; ++it) {
        int tl = it * 4 + w;
        int cb = bcs[tl];
        const float* mr = means + ((size_t)(h * NC_ + cb)) * 64;
        float df = xs[lane * 132 + tl] - mr[lane];
        part = fmaf(df, df, part);
    }
    #pragma unroll
    for (int off = 32; off > 0; off >>= 1) part += __shfl_xor(part, off);
    if (lane == 0) ar[w] = part;
    __syncthreads();
    if (tid == 0) atomicAdd(aux, ar[0] + ar[1] + ar[2] + ar[3]);
}

// ---------------------------------------------------------------------------
// K2: top-64 of 8192 — register-resident, 12-bit histogram, parallel
// suffix-scan threshold, exact candidate rank.  (unchanged, passing)
// ---------------------------------------------------------------------------
__device__ __forceinline__ unsigned flip_f32(float f) {
    unsigned bits = __float_as_uint(f);
    return (bits & 0x80000000u) ? ~bits : (bits | 0x80000000u);
}

__global__ __launch_bounds__(256)
void k_topk(const float* __restrict__ dists, int* __restrict__ qidx,
            int* __restrict__ kidx, int bh_base)
{
    __shared__ unsigned hist[4096];
    __shared__ unsigned sfx[256];
    __shared__ unsigned wtot[4];
    __shared__ unsigned cand_u[768];
    __shared__ int      cand_i[768];
    __shared__ int sh[6];

    const int tid   = threadIdx.x;
    const int c     = blockIdx.x;
    const int bhl   = blockIdx.y;
    const int which = blockIdx.z;
    const float* row = dists + ((size_t)(bhl * NC_ + c)) * T2_ + (size_t)which * T_;
    int* outp = (which ? kidx : qidx) + ((size_t)((bh_base + bhl) * NC_ + c)) * WSZ_;

    unsigned u[32];
    {
        const float4* r4 = (const float4*)row;
        #pragma unroll
        for (int it = 0; it < 8; ++it) {
            float4 f = r4[it * 256 + tid];
            u[it * 4 + 0] = flip_f32(f.x);
            u[it * 4 + 1] = flip_f32(f.y);
            u[it * 4 + 2] = flip_f32(f.z);
            u[it * 4 + 3] = flip_f32(f.w);
        }
    }
    for (int i = tid; i < 4096; i += 256) hist[i] = 0;
    if (tid < 6) sh[tid] = (tid < 2) ? -1 : 0;
    __syncthreads();

    #pragma unroll
    for (int j = 0; j < 32; ++j) atomicAdd(&hist[u[j] >> 20], 1u);
    __syncthreads();

    unsigned gs = 0;
    #pragma unroll
    for (int j = 0; j < 16; ++j) gs += hist[tid * 16 + j];

    const int l = tid & 63, w = tid >> 6;
    unsigned sv = gs;
    #pragma unroll
    for (int off = 1; off < 64; off <<= 1) {
        unsigned up = __shfl_down(sv, off);
        if (l + off < 64) sv += up;
    }
    if (l == 0) wtot[w] = sv;
    __syncthreads();
    unsigned hi = 0;
    for (int ww = w + 1; ww < 4; ++ww) hi += wtot[ww];
    unsigned suffix = sv + hi;
    sfx[tid] = suffix;
    if (suffix >= WSZ_) atomicMax(&sh[0], tid);
    __syncthreads();
    const int g1 = sh[0];
    const unsigned above_groups = (g1 < 255) ? sfx[g1 + 1] : 0u;

    if (tid < 16) {
        unsigned bs = above_groups;
        for (int j = 15; j >= tid; --j) bs += hist[g1 * 16 + j];
        if (bs >= WSZ_) atomicMax(&sh[1], g1 * 16 + tid);
    }
    __syncthreads();
    const int b1 = sh[1];
    if (tid == 0) {
        unsigned gt = above_groups;
        for (int j = b1 + 1; j <= g1 * 16 + 15; ++j) gt += hist[j];
        sh[4] = WSZ_ - (int)gt;
    }
    __syncthreads();
    const int kk = sh[4];

    #pragma unroll
    for (int j = 0; j < 32; ++j) {
        int bin = (int)(u[j] >> 20);
        int idx = (j >> 2) * 1024 + tid * 4 + (j & 3);
        if (bin > b1) {
            int p = atomicAdd(&sh[2], 1);
            outp[p] = idx;
        } else if (bin == b1) {
            int p = atomicAdd(&sh[3], 1);
            if (p < 768) { cand_u[p] = u[j]; cand_i[p] = idx; }
        }
    }
    __syncthreads();
    const int G = sh[2];
    const int C = sh[3];

    if (C <= 768) {
        for (int j = tid; j < C; j += 256) {
            unsigned uj = cand_u[j]; int ij = cand_i[j];
            int rank = 0;
            for (int ll = 0; ll < C; ++ll) {
                unsigned ul = cand_u[ll];
                rank += (int)((ul > uj) || (ul == uj && cand_i[ll] < ij));
            }
            if (rank < kk) outp[G + rank] = ij;
        }
        return;
    }

    // fallback: full 4-level radix re-reading global
    unsigned prefix = 0, mask = 0;
    int need = WSZ_;
    for (int shift = 24; shift >= 0; shift -= 8) {
        if (tid < 256) hist[tid] = 0;
        __syncthreads();
        for (int it = 0; it < 32; ++it) {
            unsigned uu = flip_f32(row[it * 256 + tid]);
            if ((uu & mask) == prefix) atomicAdd(&hist[(uu >> shift) & 255u], 1u);
        }
        __syncthreads();
        if (tid == 0) {
            int b = 255;
            int k2 = need;
            while (b > 0) {
                int cnt = (int)hist[b];
                if (k2 - cnt <= 0) break;
                k2 -= cnt; --b;
            }
            sh[0] = k2; sh[1] = b;
        }
        __syncthreads();
        need = sh[0];
        prefix |= ((unsigned)sh[1]) << shift;
        mask   |= 0xFFu << shift;
        __syncthreads();
    }
    if (tid == 0) { sh[2] = 0; sh[3] = 0; }
    __syncthreads();
    const unsigned thr = prefix;
    for (int it = 0; it < 32; ++it) {
        int i = it * 256 + tid;
        unsigned uu = flip_f32(row[i]);
        if (uu > thr) {
            int p = atomicAdd(&sh[2], 1);
            outp[p] = i;
        } else if (uu == thr) {
            int p = atomicAdd(&sh[3], 1);
            if (p < 768) cand_i[p] = i;
        }
    }
    __syncthreads();
    if (tid == 0) {
        int base = sh[2];
        int E = sh[3] < 768 ? sh[3] : 768;
        for (int n = 0; n < need; ++n) {
            int mi = 0x7fffffff, mj = 0;
            for (int j = 0; j < E; ++j) {
                int vv = cand_i[j];
                if (vv < mi) { mi = vv; mj = j; }
            }
            cand_i[mj] = 0x7fffffff;
            outp[base + n] = mi;
        }
    }
}

// ---------------------------------------------------------------------------
// K3 v7: f16 LDS staging (Q/K/V/P as half, math f32). LDS 18.9 KB -> up to
// 8 blocks/CU (was 35.3 KB / 4 blocks, occupancy-capped at 41%). Strided key
// assignment kept (2-way banks). No V-prefetch (proven neutral), no min-waves
// bound (r6/r7 spill lesson). Atomic-scatter epilogue unchanged (f32).
// grid: (NC, BH)  block: 256
// ---------------------------------------------------------------------------
__global__ __launch_bounds__(256)
void k_attn(const float* __restrict__ q, const float* __restrict__ k,
            const float* __restrict__ v, const int* __restrict__ qidx,
            const int* __restrict__ kidx, float* __restrict__ out,
            float* __restrict__ den)
{
    __shared__ __half Ah[64 * SA];   // Q (f16), then P (f16)
    __shared__ __half Bh[64 * SA];   // K (f16), then V (f16)
    __shared__ int qi[64], ki[64];

    const int tid = threadIdx.x;
    const int c  = blockIdx.x;
    const int bh = blockIdx.y;
    const int* qp = qidx + ((size_t)(bh * NC_ + c)) * WSZ_;
    const int* kp = kidx + ((size_t)(bh * NC_ + c)) * WSZ_;
    if (tid < 64) { qi[tid] = qp[tid]; ki[tid] = kp[tid]; }
    __syncthreads();

    const int grow = tid >> 2, gseg = (tid & 3) * 16;
    {
        const float4* qsrc = (const float4*)(q + ((size_t)bh * T_ + qi[grow]) * D_ + gseg);
        const float4* ksrc = (const float4*)(k + ((size_t)bh * T_ + ki[grow]) * D_ + gseg);
        unsigned* qd = (unsigned*)&Ah[grow * SA + gseg];
        unsigned* kd = (unsigned*)&Bh[grow * SA + gseg];
        #pragma unroll
        for (int j4 = 0; j4 < 4; ++j4) {
            float4 fq = qsrc[j4];
            float4 fk = ksrc[j4];
            qd[j4 * 2 + 0] = f2h2(fq.x, fq.y);
            qd[j4 * 2 + 1] = f2h2(fq.z, fq.w);
            kd[j4 * 2 + 0] = f2h2(fk.x, fk.y);
            kd[j4 * 2 + 1] = f2h2(fk.z, fk.w);
        }
    }
    __syncthreads();

    const int tx = tid & 15;
    const int ty = tid >> 4;

    // sacc[i][j] = score(row ty*4+i, key tx + 16*j)
    float sacc[4][4];
    #pragma unroll
    for (int i = 0; i < 4; ++i)
        #pragma unroll
        for (int j = 0; j < 4; ++j) sacc[i][j] = 0.f;

    for (int k4 = 0; k4 < 16; ++k4) {
        float2 qf[8];   // [i]: d-pairs (01, 23)
        #pragma unroll
        for (int i = 0; i < 4; ++i) {
            uint2 qr = *(const uint2*)&Ah[(ty * 4 + i) * SA + k4 * 4];
            qf[i * 2 + 0] = h2f(qr.x);
            qf[i * 2 + 1] = h2f(qr.y);
        }
        #pragma unroll
        for (int j = 0; j < 4; ++j) {
            uint2 kr = *(const uint2*)&Bh[(tx + j * 16) * SA + k4 * 4];
            float2 k01 = h2f(kr.x), k23 = h2f(kr.y);
            #pragma unroll
            for (int i = 0; i < 4; ++i)
                sacc[i][j] = fmaf(qf[i*2+1].y, k23.y, fmaf(qf[i*2+1].x, k23.x,
                              fmaf(qf[i*2+0].y, k01.y, fmaf(qf[i*2+0].x, k01.x, sacc[i][j]))));
        }
    }
    __syncthreads();   // K reads done -> Bh reusable

    // stage V (f32 -> f16)
    {
        const float4* vsrc = (const float4*)(v + ((size_t)bh * T_ + ki[grow]) * D_ + gseg);
        unsigned* vd = (unsigned*)&Bh[grow * SA + gseg];
        #pragma unroll
        for (int j4 = 0; j4 < 4; ++j4) {
            float4 f = vsrc[j4];
            vd[j4 * 2 + 0] = f2h2(f.x, f.y);
            vd[j4 * 2 + 1] = f2h2(f.z, f.w);
        }
    }

    float rinv[4];
    #pragma unroll
    for (int i = 0; i < 4; ++i) {
        float m = fmaxf(fmaxf(sacc[i][0], sacc[i][1]), fmaxf(sacc[i][2], sacc[i][3]));
        m = fmaxf(m, __shfl_xor(m, 1));
        m = fmaxf(m, __shfl_xor(m, 2));
        m = fmaxf(m, __shfl_xor(m, 4));
        m = fmaxf(m, __shfl_xor(m, 8));
        float e0 = expf((sacc[i][0] - m) * 0.125f);
        float e1 = expf((sacc[i][1] - m) * 0.125f);
        float e2 = expf((sacc[i][2] - m) * 0.125f);
        float e3 = expf((sacc[i][3] - m) * 0.125f);
        float s = e0 + e1 + e2 + e3;
        s += __shfl_xor(s, 1);
        s += __shfl_xor(s, 2);
        s += __shfl_xor(s, 4);
        s += __shfl_xor(s, 8);
        rinv[i] = 1.0f / s;
        const int rb = (ty * 4 + i) * SA + tx;
        Ah[rb     ] = __float2half(e0);
        Ah[rb + 16] = __float2half(e1);
        Ah[rb + 32] = __float2half(e2);
        Ah[rb + 48] = __float2half(e3);
    }
    __syncthreads();   // P stored, V staged

    float oacc[4][4];
    #pragma unroll
    for (int i = 0; i < 4; ++i)
        #pragma unroll
        for (int j = 0; j < 4; ++j) oacc[i][j] = 0.f;

    for (int jj4 = 0; jj4 < 16; ++jj4) {
        float2 v01[4], v23[4];   // [ll]: d-pairs (tx*4+0/1, tx*4+2/3) of key jj4*4+ll
        #pragma unroll
        for (int ll = 0; ll < 4; ++ll) {
            uint2 r = *(const uint2*)&Bh[(jj4 * 4 + ll) * SA + tx * 4];
            v01[ll] = h2f(r.x);
            v23[ll] = h2f(r.y);
        }
        #pragma unroll
        for (int i = 0; i < 4; ++i) {
            uint2 pr = *(const uint2*)&Ah[(ty * 4 + i) * SA + jj4 * 4];
            float2 p01 = h2f(pr.x), p23 = h2f(pr.y);
            oacc[i][0] = fmaf(p23.y, v01[3].x, fmaf(p23.x, v01[2].x, fmaf(p01.y, v01[1].x, fmaf(p01.x, v01[0].x, oacc[i][0]))));
            oacc[i][1] = fmaf(p23.y, v01[3].y, fmaf(p23.x, v01[2].y, fmaf(p01.y, v01[1].y, fmaf(p01.x, v01[0].y, oacc[i][1]))));
            oacc[i][2] = fmaf(p23.y, v23[3].x, fmaf(p23.x, v23[2].x, fmaf(p01.y, v23[1].x, fmaf(p01.x, v23[0].x, oacc[i][2]))));
            oacc[i][3] = fmaf(p23.y, v23[3].y, fmaf(p23.x, v23[2].y, fmaf(p01.y, v23[1].y, fmaf(p01.x, v23[0].y, oacc[i][3]))));
        }
    }

    #pragma unroll
    for (int i = 0; i < 4; ++i) {
        const int r = ty * 4 + i;
        float* obase = out + ((size_t)bh * T_ + qi[r]) * D_ + tx * 4;
        #pragma unroll
        for (int j = 0; j < 4; ++j) atomicAdd(obase + j, oacc[i][j] * rinv[i]);
    }
    if (tx == 0) {
        #pragma unroll
        for (int i = 0; i < 4; ++i) atomicAdd(den + (size_t)bh * T_ + qi[ty * 4 + i], 1.0f);
    }
}

// ---------------------------------------------------------------------------
// K4: out = num / (den + EPS); write aux
// ---------------------------------------------------------------------------
__global__ __launch_bounds__(256)
void k_final(float* __restrict__ out, const float* __restrict__ den,
             const float* __restrict__ aux)
{
    size_t gid = (size_t)blockIdx.x * 256 + threadIdx.x;
    float4* o4 = (float4*)out;
    float d = den[gid >> 4] + 1e-5f;
    float4 x = o4[gid];
    x.x = x.x / d; x.y = x.y / d; x.z = x.z / d; x.w = x.w / d;
    o4[gid] = x;
    if (gid == 0) out[(size_t)BH_ * T_ * D_] = aux[0] * 1.4901161193847656e-12f;
}

extern "C" void kernel_launch(void* const* d_in, const int* in_sizes, int n_in,
                              void* d_out, int out_size, void* d_ws, size_t ws_size,
                              hipStream_t stream) {
    const float* q     = (const float*)d_in[0];
    const float* k     = (const float*)d_in[1];
    const float* v     = (const float*)d_in[2];
    const float* means = (const float*)d_in[3];
    float* out = (float*)d_out;
    char*  ws  = (char*)d_ws;
    float* aux    = (float*)(ws + OFF_AUX);
    float* den    = (float*)(ws + OFF_DEN);
    int*   qidx   = (int*)(ws + OFF_QIDX);
    int*   kidx   = (int*)(ws + OFF_KIDX);
    float* meanst = (float*)(ws + OFF_MEANST);
    float* dists  = (float*)(ws + OFF_DISTS);

    hipMemsetAsync(out, 0, (size_t)((size_t)BH_ * T_ * D_ + 1) * 4, stream);
    hipMemsetAsync(ws, 0, (size_t)OFF_QIDX, stream);   // aux + den

    k_meanst<<<256, 256, 0, stream>>>(means, meanst);

    size_t region = (ws_size > OFF_DISTS) ? ws_size - (size_t)OFF_DISTS : 0;
    size_t per_bh = (size_t)NC_ * T2_ * 4;   // 8 MB
    int nbh = (int)(region / per_bh);
    nbh = nbh < 1 ? 1 : (nbh > BH_ ? BH_ : nbh);

    for (int bh_base = 0; bh_base < BH_; bh_base += nbh) {
        int cur = BH_ - bh_base < nbh ? BH_ - bh_base : nbh;
        k_dists<<<dim3(T2_ / 128, cur), 256, 0, stream>>>(q, k, means, meanst, dists, aux, bh_base);
        k_topk <<<dim3(NC_, cur, 2),    256, 0, stream>>>(dists, qidx, kidx, bh_base);
    }

    k_attn<<<dim3(NC_, BH_), 256, 0, stream>>>(q, k, v, qidx, kidx, out, den);
    k_final<<<(BH_ * T_ * D_ / 4 + 255) / 256, 256, 0, stream>>>(out, den, aux);
}

// Round 13
// 1026.380 us; speedup vs baseline: 1.2867x; 1.2611x over previous
//
#include <hip/hip_runtime.h>
#include <hip/hip_bf16.h>
#include <hip/hip_fp16.h>
#include <math.h>

#define B_ 8
#define H_ 8
#define T_ 8192
#define D_ 64
#define NC_ 128
#define WSZ_ 64
#define T2_ (2*T_)
#define BH_ (B_*H_)
#define CAP_ 16
#define SA 72   // k_attn LDS row stride in halves

// workspace layout (bytes)
#define OFF_AUX    0
#define OFF_DEN    4096                              // den (fallback) / cnt (so-path)
#define OFF_QIDX   (OFF_DEN  + BH_*T_*4)
#define OFF_KIDX   (OFF_QIDX + BH_*NC_*WSZ_*4)
#define OFF_MEANST (OFF_KIDX + BH_*NC_*WSZ_*4)
#define OFF_DISTS  (OFF_MEANST + H_*NC_*D_*4)
// dists region: nbh*NC_*T2_*4 bytes; reused after topk as:
//   so      (f16): BH*NC*WSZ*D*2 = 67.1 MB
//   entries (int): BH*T*CAP*4    = 32   MB
#define SO_BYTES      ((size_t)BH_*NC_*WSZ_*D_*2)
#define ENTRIES_BYTES ((size_t)BH_*T_*CAP_*4)

__device__ __forceinline__ float2 h2f(unsigned u) {
    __half2 h = *reinterpret_cast<__half2*>(&u);
    return __half22float2(h);
}
__device__ __forceinline__ unsigned f2h2(float a, float b) {
    __half2 h = __float22half2_rn(make_float2(a, b));
    return *reinterpret_cast<unsigned*>(&h);
}

// ---------------------------------------------------------------------------
// K0: transpose means [h][c][d] -> meanst [h][d][c]
// ---------------------------------------------------------------------------
__global__ __launch_bounds__(256)
void k_meanst(const float* __restrict__ means, float* __restrict__ meanst)
{
    int gid = blockIdx.x * 256 + threadIdx.x;
    int h = gid >> 13;
    int rem = gid & 8191;
    int d = rem >> 7;
    int c = rem & 127;
    meanst[gid] = means[((h << 7) | c) * 64 + d];
}

// ---------------------------------------------------------------------------
// K1 (r11/r12, passing): dists + argmax + aux. Bitwise-identical dists.
// grid: (T2/128, nbh)  block: 256
// ---------------------------------------------------------------------------
__global__ __launch_bounds__(256)
void k_dists(const float* __restrict__ q, const float* __restrict__ k,
             const float* __restrict__ means, const float* __restrict__ meanst,
             float* __restrict__ dists, float* __restrict__ aux, int bh_base)
{
    __shared__ float xs[64 * 132];   // [d][token], stride 132
    __shared__ int   bcs[128];
    __shared__ float ar[4];

    const int tid = threadIdx.x;
    const int bhl = blockIdx.y;
    const int bh  = bh_base + bhl;
    const int h   = bh % H_;
    const int t0  = blockIdx.x * 128;

    const int lane = tid & 63;
    const int w    = tid >> 6;
    for (int it = 0; it < 32; ++it) {
        int tl = it * 4 + w;
        int gt = t0 + tl;
        const float* src = (gt < T_)
            ? (q + ((size_t)bh * T_ + gt) * D_)
            : (k + ((size_t)bh * T_ + (gt - T_)) * D_);
        float vv = __builtin_nontemporal_load(src + lane);
        float s = vv * vv;
        #pragma unroll
        for (int off = 32; off > 0; off >>= 1) s += __shfl_xor(s, off);
        float norm = fmaxf(sqrtf(s), 1e-12f);
        xs[lane * 132 + tl] = vv / norm;
    }
    __syncthreads();

    const int ty = tid >> 4;
    const int tx = tid & 15;
    float acc[8][8];
    #pragma unroll
    for (int i = 0; i < 8; ++i)
        #pragma unroll
        for (int j = 0; j < 8; ++j) acc[i][j] = 0.f;

    const float* mt = meanst + (size_t)h * (64 * 128) + tx * 8;

    float4 mA0, mA1, mA2, mA3, mB0, mB1, mB2, mB3;
    mA0 = *(const float4*)(mt + 0);
    mA1 = *(const float4*)(mt + 4);
    mA2 = *(const float4*)(mt + 128);
    mA3 = *(const float4*)(mt + 132);

#define CDOT(dd, M0, M1) { \
    float4 xa_ = *(const float4*)&xs[(dd) * 132 + ty * 8]; \
    float4 xb_ = *(const float4*)&xs[(dd) * 132 + ty * 8 + 4]; \
    float xv_[8] = {xa_.x, xa_.y, xa_.z, xa_.w, xb_.x, xb_.y, xb_.z, xb_.w}; \
    float mv_[8] = {M0.x, M0.y, M0.z, M0.w, M1.x, M1.y, M1.z, M1.w}; \
    _Pragma("unroll") \
    for (int i_ = 0; i_ < 8; ++i_) \
        _Pragma("unroll") \
        for (int j_ = 0; j_ < 8; ++j_) \
            acc[i_][j_] = fmaf(xv_[i_], mv_[j_], acc[i_][j_]); }

    for (int g = 0; g < 32; g += 2) {
        {
            int gn = (g + 1 < 32) ? g + 1 : 31;
            const float* p = mt + gn * 256;
            mB0 = *(const float4*)(p + 0);
            mB1 = *(const float4*)(p + 4);
            mB2 = *(const float4*)(p + 128);
            mB3 = *(const float4*)(p + 132);
        }
        CDOT(2 * g,     mA0, mA1);
        CDOT(2 * g + 1, mA2, mA3);
        {
            int gn = (g + 2 < 32) ? g + 2 : 31;
            const float* p = mt + gn * 256;
            mA0 = *(const float4*)(p + 0);
            mA1 = *(const float4*)(p + 4);
            mA2 = *(const float4*)(p + 128);
            mA3 = *(const float4*)(p + 132);
        }
        CDOT(2 * g + 2, mB0, mB1);
        CDOT(2 * g + 3, mB2, mB3);
    }
#undef CDOT

    #pragma unroll
    for (int j = 0; j < 8; ++j) {
        const int c = tx * 8 + j;
        float* gp = dists + ((size_t)(bhl * NC_ + c)) * T2_ + t0 + ty * 8;
        *(float4*)gp       = make_float4(acc[0][j], acc[1][j], acc[2][j], acc[3][j]);
        *(float4*)(gp + 4) = make_float4(acc[4][j], acc[5][j], acc[6][j], acc[7][j]);
    }

    #pragma unroll
    for (int i = 0; i < 8; ++i) {
        float bv = -1e30f; int bcid = 0;
        #pragma unroll
        for (int j = 0; j < 8; ++j) {
            float vv = acc[i][j];
            if (vv > bv) { bv = vv; bcid = tx * 8 + j; }
        }
        #pragma unroll
        for (int off = 1; off < 16; off <<= 1) {
            float ov = __shfl_xor(bv, off);
            int   oc = __shfl_xor(bcid, off);
            if (ov > bv || (ov == bv && oc < bcid)) { bv = ov; bcid = oc; }
        }
        if (tx == 0) bcs[ty * 8 + i] = bcid;
    }
    __syncthreads();

    float part = 0.f;
    for (int it = 0; it < 32; ++it) {
        int tl = it * 4 + w;
        int cb = bcs[tl];
        const float* mr = means + ((size_t)(h * NC_ + cb)) * 64;
        float df = xs[lane * 132 + tl] - mr[lane];
        part = fmaf(df, df, part);
    }
    #pragma unroll
    for (int off = 32; off > 0; off >>= 1) part += __shfl_xor(part, off);
    if (lane == 0) ar[w] = part;
    __syncthreads();
    if (tid == 0) atomicAdd(aux, ar[0] + ar[1] + ar[2] + ar[3]);
}

// ---------------------------------------------------------------------------
// K2: top-64 of 8192 — register-resident, 12-bit histogram, parallel
// suffix-scan threshold, exact candidate rank.  (unchanged, passing)
// ---------------------------------------------------------------------------
__device__ __forceinline__ unsigned flip_f32(float f) {
    unsigned bits = __float_as_uint(f);
    return (bits & 0x80000000u) ? ~bits : (bits | 0x80000000u);
}

__global__ __launch_bounds__(256)
void k_topk(const float* __restrict__ dists, int* __restrict__ qidx,
            int* __restrict__ kidx, int bh_base)
{
    __shared__ unsigned hist[4096];
    __shared__ unsigned sfx[256];
    __shared__ unsigned wtot[4];
    __shared__ unsigned cand_u[768];
    __shared__ int      cand_i[768];
    __shared__ int sh[6];

    const int tid   = threadIdx.x;
    const int c     = blockIdx.x;
    const int bhl   = blockIdx.y;
    const int which = blockIdx.z;
    const float* row = dists + ((size_t)(bhl * NC_ + c)) * T2_ + (size_t)which * T_;
    int* outp = (which ? kidx : qidx) + ((size_t)((bh_base + bhl) * NC_ + c)) * WSZ_;

    unsigned u[32];
    {
        const float4* r4 = (const float4*)row;
        #pragma unroll
        for (int it = 0; it < 8; ++it) {
            float4 f = r4[it * 256 + tid];
            u[it * 4 + 0] = flip_f32(f.x);
            u[it * 4 + 1] = flip_f32(f.y);
            u[it * 4 + 2] = flip_f32(f.z);
            u[it * 4 + 3] = flip_f32(f.w);
        }
    }
    for (int i = tid; i < 4096; i += 256) hist[i] = 0;
    if (tid < 6) sh[tid] = (tid < 2) ? -1 : 0;
    __syncthreads();

    #pragma unroll
    for (int j = 0; j < 32; ++j) atomicAdd(&hist[u[j] >> 20], 1u);
    __syncthreads();

    unsigned gs = 0;
    #pragma unroll
    for (int j = 0; j < 16; ++j) gs += hist[tid * 16 + j];

    const int l = tid & 63, w = tid >> 6;
    unsigned sv = gs;
    #pragma unroll
    for (int off = 1; off < 64; off <<= 1) {
        unsigned up = __shfl_down(sv, off);
        if (l + off < 64) sv += up;
    }
    if (l == 0) wtot[w] = sv;
    __syncthreads();
    unsigned hi = 0;
    for (int ww = w + 1; ww < 4; ++ww) hi += wtot[ww];
    unsigned suffix = sv + hi;
    sfx[tid] = suffix;
    if (suffix >= WSZ_) atomicMax(&sh[0], tid);
    __syncthreads();
    const int g1 = sh[0];
    const unsigned above_groups = (g1 < 255) ? sfx[g1 + 1] : 0u;

    if (tid < 16) {
        unsigned bs = above_groups;
        for (int j = 15; j >= tid; --j) bs += hist[g1 * 16 + j];
        if (bs >= WSZ_) atomicMax(&sh[1], g1 * 16 + tid);
    }
    __syncthreads();
    const int b1 = sh[1];
    if (tid == 0) {
        unsigned gt = above_groups;
        for (int j = b1 + 1; j <= g1 * 16 + 15; ++j) gt += hist[j];
        sh[4] = WSZ_ - (int)gt;
    }
    __syncthreads();
    const int kk = sh[4];

    #pragma unroll
    for (int j = 0; j < 32; ++j) {
        int bin = (int)(u[j] >> 20);
        int idx = (j >> 2) * 1024 + tid * 4 + (j & 3);
        if (bin > b1) {
            int p = atomicAdd(&sh[2], 1);
            outp[p] = idx;
        } else if (bin == b1) {
            int p = atomicAdd(&sh[3], 1);
            if (p < 768) { cand_u[p] = u[j]; cand_i[p] = idx; }
        }
    }
    __syncthreads();
    const int G = sh[2];
    const int C = sh[3];

    if (C <= 768) {
        for (int j = tid; j < C; j += 256) {
            unsigned uj = cand_u[j]; int ij = cand_i[j];
            int rank = 0;
            for (int ll = 0; ll < C; ++ll) {
                unsigned ul = cand_u[ll];
                rank += (int)((ul > uj) || (ul == uj && cand_i[ll] < ij));
            }
            if (rank < kk) outp[G + rank] = ij;
        }
        return;
    }

    // fallback: full 4-level radix re-reading global
    unsigned prefix = 0, mask = 0;
    int need = WSZ_;
    for (int shift = 24; shift >= 0; shift -= 8) {
        if (tid < 256) hist[tid] = 0;
        __syncthreads();
        for (int it = 0; it < 32; ++it) {
            unsigned uu = flip_f32(row[it * 256 + tid]);
            if ((uu & mask) == prefix) atomicAdd(&hist[(uu >> shift) & 255u], 1u);
        }
        __syncthreads();
        if (tid == 0) {
            int b = 255;
            int k2 = need;
            while (b > 0) {
                int cnt = (int)hist[b];
                if (k2 - cnt <= 0) break;
                k2 -= cnt; --b;
            }
            sh[0] = k2; sh[1] = b;
        }
        __syncthreads();
        need = sh[0];
        prefix |= ((unsigned)sh[1]) << shift;
        mask   |= 0xFFu << shift;
        __syncthreads();
    }
    if (tid == 0) { sh[2] = 0; sh[3] = 0; }
    __syncthreads();
    const unsigned thr = prefix;
    for (int it = 0; it < 32; ++it) {
        int i = it * 256 + tid;
        unsigned uu = flip_f32(row[i]);
        if (uu > thr) {
            int p = atomicAdd(&sh[2], 1);
            outp[p] = i;
        } else if (uu == thr) {
            int p = atomicAdd(&sh[3], 1);
            if (p < 768) cand_i[p] = i;
        }
    }
    __syncthreads();
    if (tid == 0) {
        int base = sh[2];
        int E = sh[3] < 768 ? sh[3] : 768;
        for (int n = 0; n < need; ++n) {
            int mi = 0x7fffffff, mj = 0;
            for (int j = 0; j < E; ++j) {
                int vv = cand_i[j];
                if (vv < mi) { mi = vv; mj = j; }
            }
            cand_i[mj] = 0x7fffffff;
            outp[base + n] = mi;
        }
    }
}

// ---------------------------------------------------------------------------
// K3-so v4: f16 body (r12-proven: VGPR 36, LDS 18.9 KB, 0 conflicts, 70% occ)
// + so/entries gather epilogue (replaces 33.5M scattered f32 atomics with
// coalesced f16 so writes + 2M cnt atomics).
// grid: (NC, BH)  block: 256
// ---------------------------------------------------------------------------
__global__ __launch_bounds__(256)
void k_attn_w(const float* __restrict__ q, const float* __restrict__ k,
              const float* __restrict__ v, const int* __restrict__ qidx,
              const int* __restrict__ kidx, unsigned* __restrict__ so,
              int* __restrict__ cnt, int* __restrict__ entries,
              float* __restrict__ out)
{
    __shared__ __half Ah[64 * SA];   // Q (f16), then P (f16)
    __shared__ __half Bh[64 * SA];   // K (f16), then V (f16)
    __shared__ int qi[64], ki[64], lp[64];

    const int tid = threadIdx.x;
    const int c  = blockIdx.x;
    const int bh = blockIdx.y;
    const int* qp = qidx + ((size_t)(bh * NC_ + c)) * WSZ_;
    const int* kp = kidx + ((size_t)(bh * NC_ + c)) * WSZ_;
    if (tid < 64) { qi[tid] = qp[tid]; ki[tid] = kp[tid]; }
    __syncthreads();

    const int grow = tid >> 2, gseg = (tid & 3) * 16;
    {
        const float4* qsrc = (const float4*)(q + ((size_t)bh * T_ + qi[grow]) * D_ + gseg);
        const float4* ksrc = (const float4*)(k + ((size_t)bh * T_ + ki[grow]) * D_ + gseg);
        unsigned* qd = (unsigned*)&Ah[grow * SA + gseg];
        unsigned* kd = (unsigned*)&Bh[grow * SA + gseg];
        #pragma unroll
        for (int j4 = 0; j4 < 4; ++j4) {
            float4 fq = qsrc[j4];
            float4 fk = ksrc[j4];
            qd[j4 * 2 + 0] = f2h2(fq.x, fq.y);
            qd[j4 * 2 + 1] = f2h2(fq.z, fq.w);
            kd[j4 * 2 + 0] = f2h2(fk.x, fk.y);
            kd[j4 * 2 + 1] = f2h2(fk.z, fk.w);
        }
    }
    __syncthreads();

    const int tx = tid & 15;
    const int ty = tid >> 4;

    float sacc[4][4];
    #pragma unroll
    for (int i = 0; i < 4; ++i)
        #pragma unroll
        for (int j = 0; j < 4; ++j) sacc[i][j] = 0.f;

    for (int k4 = 0; k4 < 16; ++k4) {
        float2 qf[8];
        #pragma unroll
        for (int i = 0; i < 4; ++i) {
            uint2 qr = *(const uint2*)&Ah[(ty * 4 + i) * SA + k4 * 4];
            qf[i * 2 + 0] = h2f(qr.x);
            qf[i * 2 + 1] = h2f(qr.y);
        }
        #pragma unroll
        for (int j = 0; j < 4; ++j) {
            uint2 kr = *(const uint2*)&Bh[(tx + j * 16) * SA + k4 * 4];
            float2 k01 = h2f(kr.x), k23 = h2f(kr.y);
            #pragma unroll
            for (int i = 0; i < 4; ++i)
                sacc[i][j] = fmaf(qf[i*2+1].y, k23.y, fmaf(qf[i*2+1].x, k23.x,
                              fmaf(qf[i*2+0].y, k01.y, fmaf(qf[i*2+0].x, k01.x, sacc[i][j]))));
        }
    }
    __syncthreads();   // K reads done -> Bh reusable

    // stage V (f32 -> f16)
    {
        const float4* vsrc = (const float4*)(v + ((size_t)bh * T_ + ki[grow]) * D_ + gseg);
        unsigned* vd = (unsigned*)&Bh[grow * SA + gseg];
        #pragma unroll
        for (int j4 = 0; j4 < 4; ++j4) {
            float4 f = vsrc[j4];
            vd[j4 * 2 + 0] = f2h2(f.x, f.y);
            vd[j4 * 2 + 1] = f2h2(f.z, f.w);
        }
    }

    // registration (overlaps with softmax)
    if (tx == 0) {
        #pragma unroll
        for (int i = 0; i < 4; ++i) {
            int r = ty * 4 + i;
            int t = qi[r];
            int p = atomicAdd(&cnt[(size_t)bh * T_ + t], 1);
            if (p < CAP_) entries[((size_t)bh * T_ + t) * CAP_ + p] = c * WSZ_ + r;
            lp[r] = p;
        }
    }

    float rinv[4];
    #pragma unroll
    for (int i = 0; i < 4; ++i) {
        float m = fmaxf(fmaxf(sacc[i][0], sacc[i][1]), fmaxf(sacc[i][2], sacc[i][3]));
        m = fmaxf(m, __shfl_xor(m, 1));
        m = fmaxf(m, __shfl_xor(m, 2));
        m = fmaxf(m, __shfl_xor(m, 4));
        m = fmaxf(m, __shfl_xor(m, 8));
        float e0 = expf((sacc[i][0] - m) * 0.125f);
        float e1 = expf((sacc[i][1] - m) * 0.125f);
        float e2 = expf((sacc[i][2] - m) * 0.125f);
        float e3 = expf((sacc[i][3] - m) * 0.125f);
        float s = e0 + e1 + e2 + e3;
        s += __shfl_xor(s, 1);
        s += __shfl_xor(s, 2);
        s += __shfl_xor(s, 4);
        s += __shfl_xor(s, 8);
        rinv[i] = 1.0f / s;
        const int rb = (ty * 4 + i) * SA + tx;
        Ah[rb     ] = __float2half(e0);
        Ah[rb + 16] = __float2half(e1);
        Ah[rb + 32] = __float2half(e2);
        Ah[rb + 48] = __float2half(e3);
    }
    __syncthreads();   // P stored, V staged, lp valid

    float oacc[4][4];
    #pragma unroll
    for (int i = 0; i < 4; ++i)
        #pragma unroll
        for (int j = 0; j < 4; ++j) oacc[i][j] = 0.f;

    for (int jj4 = 0; jj4 < 16; ++jj4) {
        float2 v01[4], v23[4];
        #pragma unroll
        for (int ll = 0; ll < 4; ++ll) {
            uint2 r = *(const uint2*)&Bh[(jj4 * 4 + ll) * SA + tx * 4];
            v01[ll] = h2f(r.x);
            v23[ll] = h2f(r.y);
        }
        #pragma unroll
        for (int i = 0; i < 4; ++i) {
            uint2 pr = *(const uint2*)&Ah[(ty * 4 + i) * SA + jj4 * 4];
            float2 p01 = h2f(pr.x), p23 = h2f(pr.y);
            oacc[i][0] = fmaf(p23.y, v01[3].x, fmaf(p23.x, v01[2].x, fmaf(p01.y, v01[1].x, fmaf(p01.x, v01[0].x, oacc[i][0]))));
            oacc[i][1] = fmaf(p23.y, v01[3].y, fmaf(p23.x, v01[2].y, fmaf(p01.y, v01[1].y, fmaf(p01.x, v01[0].y, oacc[i][1]))));
            oacc[i][2] = fmaf(p23.y, v23[3].x, fmaf(p23.x, v23[2].x, fmaf(p01.y, v23[1].x, fmaf(p01.x, v23[0].x, oacc[i][2]))));
            oacc[i][3] = fmaf(p23.y, v23[3].y, fmaf(p23.x, v23[2].y, fmaf(p01.y, v23[1].y, fmaf(p01.x, v23[0].y, oacc[i][3]))));
        }
    }

    // emit so rows (coalesced uint2 = 4 f16); rare overflow also atomics out
    #pragma unroll
    for (int i = 0; i < 4; ++i) {
        const int r = ty * 4 + i;
        float o0 = oacc[i][0] * rinv[i];
        float o1 = oacc[i][1] * rinv[i];
        float o2 = oacc[i][2] * rinv[i];
        float o3 = oacc[i][3] * rinv[i];
        unsigned* dst = so + (((size_t)(bh * NC_ + c)) * WSZ_ + r) * (D_ / 2) + tx * 2;
        uint2 pk;
        pk.x = f2h2(o0, o1);
        pk.y = f2h2(o2, o3);
        *(uint2*)dst = pk;
        if (lp[r] >= CAP_) {
            float* ob = out + ((size_t)bh * T_ + qi[r]) * D_ + tx * 4;
            atomicAdd(ob + 0, o0); atomicAdd(ob + 1, o1);
            atomicAdd(ob + 2, o2); atomicAdd(ob + 3, o3);
        }
    }
}

// ---------------------------------------------------------------------------
// K4-so: gather finalize: out[t] = (sum of so rows + overflow)/(n+eps) + aux
// grid: (T/16, BH)  block: 256
// ---------------------------------------------------------------------------
__global__ __launch_bounds__(256)
void k_gather(const unsigned* __restrict__ so, const int* __restrict__ cnt,
              const int* __restrict__ entries, float* __restrict__ out,
              const float* __restrict__ aux)
{
    const int tid = threadIdx.x;
    const int tk  = blockIdx.x * 16 + (tid >> 4);
    const int bh  = blockIdx.y;
    const int d4  = (tid & 15) * 2;     // uint pairs (4 f16)
    const size_t tix = (size_t)bh * T_ + tk;

    const int n = cnt[tix];
    const int m = n < CAP_ ? n : CAP_;
    const int* ep = entries + tix * CAP_;

    float a0 = 0.f, a1 = 0.f, a2 = 0.f, a3 = 0.f;
    for (int j = 0; j < m; ++j) {
        int e = ep[j];
        const unsigned* sp = so + ((size_t)bh * (NC_ * WSZ_) + e) * (D_ / 2) + d4;
        uint2 raw = *(const uint2*)sp;
        float2 f01 = h2f(raw.x), f23 = h2f(raw.y);
        a0 += f01.x; a1 += f01.y; a2 += f23.x; a3 += f23.y;
    }
    float* op = out + tix * D_ + (tid & 15) * 4;
    float4 pr = *(float4*)op;                 // overflow base (normally 0)
    float inv = 1.0f / ((float)n + 1e-5f);
    float4 r;
    r.x = (a0 + pr.x) * inv;
    r.y = (a1 + pr.y) * inv;
    r.z = (a2 + pr.z) * inv;
    r.w = (a3 + pr.w) * inv;
    *(float4*)op = r;

    if (blockIdx.x == 0 && bh == 0 && tid == 0)
        out[(size_t)BH_ * T_ * D_] = aux[0] * 1.4901161193847656e-12f;
}

// ---------------------------------------------------------------------------
// K3/K4 fallback (small-ws): r12 f16 atomic-scatter path
// ---------------------------------------------------------------------------
__global__ __launch_bounds__(256)
void k_attn(const float* __restrict__ q, const float* __restrict__ k,
            const float* __restrict__ v, const int* __restrict__ qidx,
            const int* __restrict__ kidx, float* __restrict__ out,
            float* __restrict__ den)
{
    __shared__ __half Ah[64 * SA];
    __shared__ __half Bh[64 * SA];
    __shared__ int qi[64], ki[64];

    const int tid = threadIdx.x;
    const int c  = blockIdx.x;
    const int bh = blockIdx.y;
    const int* qp = qidx + ((size_t)(bh * NC_ + c)) * WSZ_;
    const int* kp = kidx + ((size_t)(bh * NC_ + c)) * WSZ_;
    if (tid < 64) { qi[tid] = qp[tid]; ki[tid] = kp[tid]; }
    __syncthreads();

    const int grow = tid >> 2, gseg = (tid & 3) * 16;
    {
        const float4* qsrc = (const float4*)(q + ((size_t)bh * T_ + qi[grow]) * D_ + gseg);
        const float4* ksrc = (const float4*)(k + ((size_t)bh * T_ + ki[grow]) * D_ + gseg);
        unsigned* qd = (unsigned*)&Ah[grow * SA + gseg];
        unsigned* kd = (unsigned*)&Bh[grow * SA + gseg];
        #pragma unroll
        for (int j4 = 0; j4 < 4; ++j4) {
            float4 fq = qsrc[j4];
            float4 fk = ksrc[j4];
            qd[j4 * 2 + 0] = f2h2(fq.x, fq.y);
            qd[j4 * 2 + 1] = f2h2(fq.z, fq.w);
            kd[j4 * 2 + 0] = f2h2(fk.x, fk.y);
            kd[j4 * 2 + 1] = f2h2(fk.z, fk.w);
        }
    }
    __syncthreads();

    const int tx = tid & 15;
    const int ty = tid >> 4;

    float sacc[4][4];
    #pragma unroll
    for (int i = 0; i < 4; ++i)
        #pragma unroll
        for (int j = 0; j < 4; ++j) sacc[i][j] = 0.f;

    for (int k4 = 0; k4 < 16; ++k4) {
        float2 qf[8];
        #pragma unroll
        for (int i = 0; i < 4; ++i) {
            uint2 qr = *(const uint2*)&Ah[(ty * 4 + i) * SA + k4 * 4];
            qf[i * 2 + 0] = h2f(qr.x);
            qf[i * 2 + 1] = h2f(qr.y);
        }
        #pragma unroll
        for (int j = 0; j < 4; ++j) {
            uint2 kr = *(const uint2*)&Bh[(tx + j * 16) * SA + k4 * 4];
            float2 k01 = h2f(kr.x), k23 = h2f(kr.y);
            #pragma unroll
            for (int i = 0; i < 4; ++i)
                sacc[i][j] = fmaf(qf[i*2+1].y, k23.y, fmaf(qf[i*2+1].x, k23.x,
                              fmaf(qf[i*2+0].y, k01.y, fmaf(qf[i*2+0].x, k01.x, sacc[i][j]))));
        }
    }
    __syncthreads();

    {
        const float4* vsrc = (const float4*)(v + ((size_t)bh * T_ + ki[grow]) * D_ + gseg);
        unsigned* vd = (unsigned*)&Bh[grow * SA + gseg];
        #pragma unroll
        for (int j4 = 0; j4 < 4; ++j4) {
            float4 f = vsrc[j4];
            vd[j4 * 2 + 0] = f2h2(f.x, f.y);
            vd[j4 * 2 + 1] = f2h2(f.z, f.w);
        }
    }

    float rinv[4];
    #pragma unroll
    for (int i = 0; i < 4; ++i) {
        float m = fmaxf(fmaxf(sacc[i][0], sacc[i][1]), fmaxf(sacc[i][2], sacc[i][3]));
        m = fmaxf(m, __shfl_xor(m, 1));
        m = fmaxf(m, __shfl_xor(m, 2));
        m = fmaxf(m, __shfl_xor(m, 4));
        m = fmaxf(m, __shfl_xor(m, 8));
        float e0 = expf((sacc[i][0] - m) * 0.125f);
        float e1 = expf((sacc[i][1] - m) * 0.125f);
        float e2 = expf((sacc[i][2] - m) * 0.125f);
        float e3 = expf((sacc[i][3] - m) * 0.125f);
        float s = e0 + e1 + e2 + e3;
        s += __shfl_xor(s, 1);
        s += __shfl_xor(s, 2);
        s += __shfl_xor(s, 4);
        s += __shfl_xor(s, 8);
        rinv[i] = 1.0f / s;
        const int rb = (ty * 4 + i) * SA + tx;
        Ah[rb     ] = __float2half(e0);
        Ah[rb + 16] = __float2half(e1);
        Ah[rb + 32] = __float2half(e2);
        Ah[rb + 48] = __float2half(e3);
    }
    __syncthreads();

    float oacc[4][4];
    #pragma unroll
    for (int i = 0; i < 4; ++i)
        #pragma unroll
        for (int j = 0; j < 4; ++j) oacc[i][j] = 0.f;

    for (int jj4 = 0; jj4 < 16; ++jj4) {
        float2 v01[4], v23[4];
        #pragma unroll
        for (int ll = 0; ll < 4; ++ll) {
            uint2 r = *(const uint2*)&Bh[(jj4 * 4 + ll) * SA + tx * 4];
            v01[ll] = h2f(r.x);
            v23[ll] = h2f(r.y);
        }
        #pragma unroll
        for (int i = 0; i < 4; ++i) {
            uint2 pr = *(const uint2*)&Ah[(ty * 4 + i) * SA + jj4 * 4];
            float2 p01 = h2f(pr.x), p23 = h2f(pr.y);
            oacc[i][0] = fmaf(p23.y, v01[3].x, fmaf(p23.x, v01[2].x, fmaf(p01.y, v01[1].x, fmaf(p01.x, v01[0].x, oacc[i][0]))));
            oacc[i][1] = fmaf(p23.y, v01[3].y, fmaf(p23.x, v01[2].y, fmaf(p01.y, v01[1].y, fmaf(p01.x, v01[0].y, oacc[i][1]))));
            oacc[i][2] = fmaf(p23.y, v23[3].x, fmaf(p23.x, v23[2].x, fmaf(p01.y, v23[1].x, fmaf(p01.x, v23[0].x, oacc[i][2]))));
            oacc[i][3] = fmaf(p23.y, v23[3].y, fmaf(p23.x, v23[2].y, fmaf(p01.y, v23[1].y, fmaf(p01.x, v23[0].y, oacc[i][3]))));
        }
    }

    #pragma unroll
    for (int i = 0; i < 4; ++i) {
        const int r = ty * 4 + i;
        float* obase = out + ((size_t)bh * T_ + qi[r]) * D_ + tx * 4;
        #pragma unroll
        for (int j = 0; j < 4; ++j) atomicAdd(obase + j, oacc[i][j] * rinv[i]);
    }
    if (tx == 0) {
        #pragma unroll
        for (int i = 0; i < 4; ++i) atomicAdd(den + (size_t)bh * T_ + qi[ty * 4 + i], 1.0f);
    }
}

__global__ __launch_bounds__(256)
void k_final(float* __restrict__ out, const float* __restrict__ den,
             const float* __restrict__ aux)
{
    size_t gid = (size_t)blockIdx.x * 256 + threadIdx.x;
    float4* o4 = (float4*)out;
    float d = den[gid >> 4] + 1e-5f;
    float4 x = o4[gid];
    x.x = x.x / d; x.y = x.y / d; x.z = x.z / d; x.w = x.w / d;
    o4[gid] = x;
    if (gid == 0) out[(size_t)BH_ * T_ * D_] = aux[0] * 1.4901161193847656e-12f;
}

extern "C" void kernel_launch(void* const* d_in, const int* in_sizes, int n_in,
                              void* d_out, int out_size, void* d_ws, size_t ws_size,
                              hipStream_t stream) {
    const float* q     = (const float*)d_in[0];
    const float* k     = (const float*)d_in[1];
    const float* v     = (const float*)d_in[2];
    const float* means = (const float*)d_in[3];
    float* out = (float*)d_out;
    char*  ws  = (char*)d_ws;
    float* aux    = (float*)(ws + OFF_AUX);
    float* den    = (float*)(ws + OFF_DEN);     // cnt (int) in so-path
    int*   qidx   = (int*)(ws + OFF_QIDX);
    int*   kidx   = (int*)(ws + OFF_KIDX);
    float* meanst = (float*)(ws + OFF_MEANST);
    float* dists  = (float*)(ws + OFF_DISTS);

    hipMemsetAsync(out, 0, (size_t)((size_t)BH_ * T_ * D_ + 1) * 4, stream);
    hipMemsetAsync(ws, 0, (size_t)OFF_QIDX, stream);   // aux + den/cnt

    k_meanst<<<256, 256, 0, stream>>>(means, meanst);

    size_t region = (ws_size > OFF_DISTS) ? ws_size - (size_t)OFF_DISTS : 0;
    size_t per_bh = (size_t)NC_ * T2_ * 4;   // 8 MB
    int nbh = (int)(region / per_bh);
    nbh = nbh < 1 ? 1 : (nbh > BH_ ? BH_ : nbh);
    const bool sopath = region >= (SO_BYTES + ENTRIES_BYTES);

    for (int bh_base = 0; bh_base < BH_; bh_base += nbh) {
        int cur = BH_ - bh_base < nbh ? BH_ - bh_base : nbh;
        k_dists<<<dim3(T2_ / 128, cur), 256, 0, stream>>>(q, k, means, meanst, dists, aux, bh_base);
        k_topk <<<dim3(NC_, cur, 2),    256, 0, stream>>>(dists, qidx, kidx, bh_base);
    }

    if (sopath) {
        unsigned* so = (unsigned*)(ws + OFF_DISTS);
        int* entries = (int*)(ws + OFF_DISTS + SO_BYTES);
        k_attn_w<<<dim3(NC_, BH_), 256, 0, stream>>>(q, k, v, qidx, kidx,
                                                     so, (int*)den, entries, out);
        k_gather<<<dim3(T_ / 16, BH_), 256, 0, stream>>>(so, (int*)den, entries, out, aux);
    } else {
        k_attn<<<dim3(NC_, BH_), 256, 0, stream>>>(q, k, v, qidx, kidx, out, den);
        k_final<<<(BH_ * T_ * D_ / 4 + 255) / 256, 256, 0, stream>>>(out, den, aux);
    }
}

// Round 14
// 1002.843 us; speedup vs baseline: 1.3169x; 1.0235x over previous
//
#include <hip/hip_runtime.h>
#include <hip/hip_bf16.h>
#include <hip/hip_fp16.h>
#include <math.h>

#define B_ 8
#define H_ 8
#define T_ 8192
#define D_ 64
#define NC_ 128
#define WSZ_ 64
#define T2_ (2*T_)
#define BH_ (B_*H_)
#define CAP_ 16
#define SA 72   // k_attn LDS row stride in halves

// workspace layout (bytes)
#define OFF_AUX    0
#define OFF_DEN    4096                              // den (fallback) / cnt (so-path)
#define OFF_QIDX   (OFF_DEN  + BH_*T_*4)
#define OFF_KIDX   (OFF_QIDX + BH_*NC_*WSZ_*4)
#define OFF_MEANST (OFF_KIDX + BH_*NC_*WSZ_*4)
#define OFF_DISTS  (OFF_MEANST + H_*NC_*D_*4)
// dists region: nbh*NC_*T2_*4 bytes; reused after topk as:
//   so      (f16): BH*NC*WSZ*D*2 = 67.1 MB
//   entries (int): BH*T*CAP*4    = 32   MB
#define SO_BYTES      ((size_t)BH_*NC_*WSZ_*D_*2)
#define ENTRIES_BYTES ((size_t)BH_*T_*CAP_*4)

__device__ __forceinline__ float2 h2f(unsigned u) {
    __half2 h = *reinterpret_cast<__half2*>(&u);
    return __half22float2(h);
}
__device__ __forceinline__ unsigned f2h2(float a, float b) {
    __half2 h = __float22half2_rn(make_float2(a, b));
    return *reinterpret_cast<unsigned*>(&h);
}

// ---------------------------------------------------------------------------
// K0: transpose means [h][c][d] -> meanst [h][d][c]
// ---------------------------------------------------------------------------
__global__ __launch_bounds__(256)
void k_meanst(const float* __restrict__ means, float* __restrict__ meanst)
{
    int gid = blockIdx.x * 256 + threadIdx.x;
    int h = gid >> 13;
    int rem = gid & 8191;
    int d = rem >> 7;
    int c = rem & 127;
    meanst[gid] = means[((h << 7) | c) * 64 + d];
}

// ---------------------------------------------------------------------------
// K1 v7: 64-token blocks (was 128). LDS 17.4 KB (was 34.8) -> 8+ blocks/CU;
// per-thread tile 4tok x 8clu -> acc 32 VGPR, target <=64 total for 8 w/SIMD.
// No prefetch (TLP replaces ILP at high occupancy). Per-(token,cluster) FMA
// chain is a single ascending-d fmaf chain -> bitwise-identical dists.
// grid: (T2/64, nbh)  block: 256
// ---------------------------------------------------------------------------
__global__ __launch_bounds__(256)
void k_dists(const float* __restrict__ q, const float* __restrict__ k,
             const float* __restrict__ means, const float* __restrict__ meanst,
             float* __restrict__ dists, float* __restrict__ aux, int bh_base)
{
    __shared__ float xs[64 * 68];    // [d][token(64)], stride 68
    __shared__ int   bcs[64];
    __shared__ float ar[4];

    const int tid = threadIdx.x;
    const int bhl = blockIdx.y;
    const int bh  = bh_base + bhl;
    const int h   = bh % H_;
    const int t0  = blockIdx.x * 64;

    // ---- phase 1: load 64 token rows (nt), normalize, store transposed
    const int lane = tid & 63;
    const int w    = tid >> 6;
    for (int it = 0; it < 16; ++it) {
        int tl = it * 4 + w;
        int gt = t0 + tl;
        const float* src = (gt < T_)
            ? (q + ((size_t)bh * T_ + gt) * D_)
            : (k + ((size_t)bh * T_ + (gt - T_)) * D_);
        float vv = __builtin_nontemporal_load(src + lane);
        float s = vv * vv;
        #pragma unroll
        for (int off = 32; off > 0; off >>= 1) s += __shfl_xor(s, off);
        float norm = fmaxf(sqrtf(s), 1e-12f);
        xs[lane * 68 + tl] = vv / norm;
    }
    __syncthreads();

    // ---- phase 2: 4tok x 8clu tile per thread over d
    const int ty = tid >> 4;     // token group: tokens ty*4..+3
    const int tx = tid & 15;     // cluster group: clusters tx*8..+7
    float acc[4][8];
    #pragma unroll
    for (int i = 0; i < 4; ++i)
        #pragma unroll
        for (int j = 0; j < 8; ++j) acc[i][j] = 0.f;

    const float* mt = meanst + (size_t)h * (64 * 128) + tx * 8;
    #pragma unroll 4
    for (int d = 0; d < 64; ++d) {
        float4 ma = *(const float4*)(mt + d * 128);
        float4 mb = *(const float4*)(mt + d * 128 + 4);
        float4 xa = *(const float4*)&xs[d * 68 + ty * 4];
        float xv[4] = {xa.x, xa.y, xa.z, xa.w};
        float mv[8] = {ma.x, ma.y, ma.z, ma.w, mb.x, mb.y, mb.z, mb.w};
        #pragma unroll
        for (int i = 0; i < 4; ++i)
            #pragma unroll
            for (int j = 0; j < 8; ++j)
                acc[i][j] = fmaf(xv[i], mv[j], acc[i][j]);
    }

    // ---- phase 3: direct transposed global store
    #pragma unroll
    for (int j = 0; j < 8; ++j) {
        const int c = tx * 8 + j;
        float* gp = dists + ((size_t)(bhl * NC_ + c)) * T2_ + t0 + ty * 4;
        *(float4*)gp = make_float4(acc[0][j], acc[1][j], acc[2][j], acc[3][j]);
    }

    // ---- phase 4: argmax across clusters (16-lane groups share tokens)
    #pragma unroll
    for (int i = 0; i < 4; ++i) {
        float bv = -1e30f; int bcid = 0;
        #pragma unroll
        for (int j = 0; j < 8; ++j) {
            float vv = acc[i][j];
            if (vv > bv) { bv = vv; bcid = tx * 8 + j; }
        }
        #pragma unroll
        for (int off = 1; off < 16; off <<= 1) {
            float ov = __shfl_xor(bv, off);
            int   oc = __shfl_xor(bcid, off);
            if (ov > bv || (ov == bv && oc < bcid)) { bv = ov; bcid = oc; }
        }
        if (tx == 0) bcs[ty * 4 + i] = bcid;
    }
    __syncthreads();

    // ---- phase 5: aux = sum (xn - mean_best)^2
    float part = 0.f;
    for (int it = 0; it < 16; ++it) {
        int tl = it * 4 + w;
        int cb = bcs[tl];
        const float* mr = means + ((size_t)(h * NC_ + cb)) * 64;
        float df = xs[lane * 68 + tl] - mr[lane];
        part = fmaf(df, df, part);
    }
    #pragma unroll
    for (int off = 32; off > 0; off >>= 1) part += __shfl_xor(part, off);
    if (lane == 0) ar[w] = part;
    __syncthreads();
    if (tid == 0) atomicAdd(aux, ar[0] + ar[1] + ar[2] + ar[3]);
}

// ---------------------------------------------------------------------------
// K2: top-64 of 8192 — register-resident, 12-bit histogram, parallel
// suffix-scan threshold, exact candidate rank.  (unchanged, passing)
// ---------------------------------------------------------------------------
__device__ __forceinline__ unsigned flip_f32(float f) {
    unsigned bits = __float_as_uint(f);
    return (bits & 0x80000000u) ? ~bits : (bits | 0x80000000u);
}

__global__ __launch_bounds__(256)
void k_topk(const float* __restrict__ dists, int* __restrict__ qidx,
            int* __restrict__ kidx, int bh_base)
{
    __shared__ unsigned hist[4096];
    __shared__ unsigned sfx[256];
    __shared__ unsigned wtot[4];
    __shared__ unsigned cand_u[768];
    __shared__ int      cand_i[768];
    __shared__ int sh[6];

    const int tid   = threadIdx.x;
    const int c     = blockIdx.x;
    const int bhl   = blockIdx.y;
    const int which = blockIdx.z;
    const float* row = dists + ((size_t)(bhl * NC_ + c)) * T2_ + (size_t)which * T_;
    int* outp = (which ? kidx : qidx) + ((size_t)((bh_base + bhl) * NC_ + c)) * WSZ_;

    unsigned u[32];
    {
        const float4* r4 = (const float4*)row;
        #pragma unroll
        for (int it = 0; it < 8; ++it) {
            float4 f = r4[it * 256 + tid];
            u[it * 4 + 0] = flip_f32(f.x);
            u[it * 4 + 1] = flip_f32(f.y);
            u[it * 4 + 2] = flip_f32(f.z);
            u[it * 4 + 3] = flip_f32(f.w);
        }
    }
    for (int i = tid; i < 4096; i += 256) hist[i] = 0;
    if (tid < 6) sh[tid] = (tid < 2) ? -1 : 0;
    __syncthreads();

    #pragma unroll
    for (int j = 0; j < 32; ++j) atomicAdd(&hist[u[j] >> 20], 1u);
    __syncthreads();

    unsigned gs = 0;
    #pragma unroll
    for (int j = 0; j < 16; ++j) gs += hist[tid * 16 + j];

    const int l = tid & 63, w = tid >> 6;
    unsigned sv = gs;
    #pragma unroll
    for (int off = 1; off < 64; off <<= 1) {
        unsigned up = __shfl_down(sv, off);
        if (l + off < 64) sv += up;
    }
    if (l == 0) wtot[w] = sv;
    __syncthreads();
    unsigned hi = 0;
    for (int ww = w + 1; ww < 4; ++ww) hi += wtot[ww];
    unsigned suffix = sv + hi;
    sfx[tid] = suffix;
    if (suffix >= WSZ_) atomicMax(&sh[0], tid);
    __syncthreads();
    const int g1 = sh[0];
    const unsigned above_groups = (g1 < 255) ? sfx[g1 + 1] : 0u;

    if (tid < 16) {
        unsigned bs = above_groups;
        for (int j = 15; j >= tid; --j) bs += hist[g1 * 16 + j];
        if (bs >= WSZ_) atomicMax(&sh[1], g1 * 16 + tid);
    }
    __syncthreads();
    const int b1 = sh[1];
    if (tid == 0) {
        unsigned gt = above_groups;
        for (int j = b1 + 1; j <= g1 * 16 + 15; ++j) gt += hist[j];
        sh[4] = WSZ_ - (int)gt;
    }
    __syncthreads();
    const int kk = sh[4];

    #pragma unroll
    for (int j = 0; j < 32; ++j) {
        int bin = (int)(u[j] >> 20);
        int idx = (j >> 2) * 1024 + tid * 4 + (j & 3);
        if (bin > b1) {
            int p = atomicAdd(&sh[2], 1);
            outp[p] = idx;
        } else if (bin == b1) {
            int p = atomicAdd(&sh[3], 1);
            if (p < 768) { cand_u[p] = u[j]; cand_i[p] = idx; }
        }
    }
    __syncthreads();
    const int G = sh[2];
    const int C = sh[3];

    if (C <= 768) {
        for (int j = tid; j < C; j += 256) {
            unsigned uj = cand_u[j]; int ij = cand_i[j];
            int rank = 0;
            for (int ll = 0; ll < C; ++ll) {
                unsigned ul = cand_u[ll];
                rank += (int)((ul > uj) || (ul == uj && cand_i[ll] < ij));
            }
            if (rank < kk) outp[G + rank] = ij;
        }
        return;
    }

    // fallback: full 4-level radix re-reading global
    unsigned prefix = 0, mask = 0;
    int need = WSZ_;
    for (int shift = 24; shift >= 0; shift -= 8) {
        if (tid < 256) hist[tid] = 0;
        __syncthreads();
        for (int it = 0; it < 32; ++it) {
            unsigned uu = flip_f32(row[it * 256 + tid]);
            if ((uu & mask) == prefix) atomicAdd(&hist[(uu >> shift) & 255u], 1u);
        }
        __syncthreads();
        if (tid == 0) {
            int b = 255;
            int k2 = need;
            while (b > 0) {
                int cnt = (int)hist[b];
                if (k2 - cnt <= 0) break;
                k2 -= cnt; --b;
            }
            sh[0] = k2; sh[1] = b;
        }
        __syncthreads();
        need = sh[0];
        prefix |= ((unsigned)sh[1]) << shift;
        mask   |= 0xFFu << shift;
        __syncthreads();
    }
    if (tid == 0) { sh[2] = 0; sh[3] = 0; }
    __syncthreads();
    const unsigned thr = prefix;
    for (int it = 0; it < 32; ++it) {
        int i = it * 256 + tid;
        unsigned uu = flip_f32(row[i]);
        if (uu > thr) {
            int p = atomicAdd(&sh[2], 1);
            outp[p] = i;
        } else if (uu == thr) {
            int p = atomicAdd(&sh[3], 1);
            if (p < 768) cand_i[p] = i;
        }
    }
    __syncthreads();
    if (tid == 0) {
        int base = sh[2];
        int E = sh[3] < 768 ? sh[3] : 768;
        for (int n = 0; n < need; ++n) {
            int mi = 0x7fffffff, mj = 0;
            for (int j = 0; j < E; ++j) {
                int vv = cand_i[j];
                if (vv < mi) { mi = vv; mj = j; }
            }
            cand_i[mj] = 0x7fffffff;
            outp[base + n] = mi;
        }
    }
}

// ---------------------------------------------------------------------------
// K3-so v4 (r13, passing): f16 body + so/entries gather epilogue.
// grid: (NC, BH)  block: 256
// ---------------------------------------------------------------------------
__global__ __launch_bounds__(256)
void k_attn_w(const float* __restrict__ q, const float* __restrict__ k,
              const float* __restrict__ v, const int* __restrict__ qidx,
              const int* __restrict__ kidx, unsigned* __restrict__ so,
              int* __restrict__ cnt, int* __restrict__ entries,
              float* __restrict__ out)
{
    __shared__ __half Ah[64 * SA];   // Q (f16), then P (f16)
    __shared__ __half Bh[64 * SA];   // K (f16), then V (f16)
    __shared__ int qi[64], ki[64], lp[64];

    const int tid = threadIdx.x;
    const int c  = blockIdx.x;
    const int bh = blockIdx.y;
    const int* qp = qidx + ((size_t)(bh * NC_ + c)) * WSZ_;
    const int* kp = kidx + ((size_t)(bh * NC_ + c)) * WSZ_;
    if (tid < 64) { qi[tid] = qp[tid]; ki[tid] = kp[tid]; }
    __syncthreads();

    const int grow = tid >> 2, gseg = (tid & 3) * 16;
    {
        const float4* qsrc = (const float4*)(q + ((size_t)bh * T_ + qi[grow]) * D_ + gseg);
        const float4* ksrc = (const float4*)(k + ((size_t)bh * T_ + ki[grow]) * D_ + gseg);
        unsigned* qd = (unsigned*)&Ah[grow * SA + gseg];
        unsigned* kd = (unsigned*)&Bh[grow * SA + gseg];
        #pragma unroll
        for (int j4 = 0; j4 < 4; ++j4) {
            float4 fq = qsrc[j4];
            float4 fk = ksrc[j4];
            qd[j4 * 2 + 0] = f2h2(fq.x, fq.y);
            qd[j4 * 2 + 1] = f2h2(fq.z, fq.w);
            kd[j4 * 2 + 0] = f2h2(fk.x, fk.y);
            kd[j4 * 2 + 1] = f2h2(fk.z, fk.w);
        }
    }
    __syncthreads();

    const int tx = tid & 15;
    const int ty = tid >> 4;

    float sacc[4][4];
    #pragma unroll
    for (int i = 0; i < 4; ++i)
        #pragma unroll
        for (int j = 0; j < 4; ++j) sacc[i][j] = 0.f;

    for (int k4 = 0; k4 < 16; ++k4) {
        float2 qf[8];
        #pragma unroll
        for (int i = 0; i < 4; ++i) {
            uint2 qr = *(const uint2*)&Ah[(ty * 4 + i) * SA + k4 * 4];
            qf[i * 2 + 0] = h2f(qr.x);
            qf[i * 2 + 1] = h2f(qr.y);
        }
        #pragma unroll
        for (int j = 0; j < 4; ++j) {
            uint2 kr = *(const uint2*)&Bh[(tx + j * 16) * SA + k4 * 4];
            float2 k01 = h2f(kr.x), k23 = h2f(kr.y);
            #pragma unroll
            for (int i = 0; i < 4; ++i)
                sacc[i][j] = fmaf(qf[i*2+1].y, k23.y, fmaf(qf[i*2+1].x, k23.x,
                              fmaf(qf[i*2+0].y, k01.y, fmaf(qf[i*2+0].x, k01.x, sacc[i][j]))));
        }
    }
    __syncthreads();   // K reads done -> Bh reusable

    // stage V (f32 -> f16)
    {
        const float4* vsrc = (const float4*)(v + ((size_t)bh * T_ + ki[grow]) * D_ + gseg);
        unsigned* vd = (unsigned*)&Bh[grow * SA + gseg];
        #pragma unroll
        for (int j4 = 0; j4 < 4; ++j4) {
            float4 f = vsrc[j4];
            vd[j4 * 2 + 0] = f2h2(f.x, f.y);
            vd[j4 * 2 + 1] = f2h2(f.z, f.w);
        }
    }

    // registration (overlaps with softmax)
    if (tx == 0) {
        #pragma unroll
        for (int i = 0; i < 4; ++i) {
            int r = ty * 4 + i;
            int t = qi[r];
            int p = atomicAdd(&cnt[(size_t)bh * T_ + t], 1);
            if (p < CAP_) entries[((size_t)bh * T_ + t) * CAP_ + p] = c * WSZ_ + r;
            lp[r] = p;
        }
    }

    float rinv[4];
    #pragma unroll
    for (int i = 0; i < 4; ++i) {
        float m = fmaxf(fmaxf(sacc[i][0], sacc[i][1]), fmaxf(sacc[i][2], sacc[i][3]));
        m = fmaxf(m, __shfl_xor(m, 1));
        m = fmaxf(m, __shfl_xor(m, 2));
        m = fmaxf(m, __shfl_xor(m, 4));
        m = fmaxf(m, __shfl_xor(m, 8));
        float e0 = expf((sacc[i][0] - m) * 0.125f);
        float e1 = expf((sacc[i][1] - m) * 0.125f);
        float e2 = expf((sacc[i][2] - m) * 0.125f);
        float e3 = expf((sacc[i][3] - m) * 0.125f);
        float s = e0 + e1 + e2 + e3;
        s += __shfl_xor(s, 1);
        s += __shfl_xor(s, 2);
        s += __shfl_xor(s, 4);
        s += __shfl_xor(s, 8);
        rinv[i] = 1.0f / s;
        const int rb = (ty * 4 + i) * SA + tx;
        Ah[rb     ] = __float2half(e0);
        Ah[rb + 16] = __float2half(e1);
        Ah[rb + 32] = __float2half(e2);
        Ah[rb + 48] = __float2half(e3);
    }
    __syncthreads();   // P stored, V staged, lp valid

    float oacc[4][4];
    #pragma unroll
    for (int i = 0; i < 4; ++i)
        #pragma unroll
        for (int j = 0; j < 4; ++j) oacc[i][j] = 0.f;

    for (int jj4 = 0; jj4 < 16; ++jj4) {
        float2 v01[4], v23[4];
        #pragma unroll
        for (int ll = 0; ll < 4; ++ll) {
            uint2 r = *(const uint2*)&Bh[(jj4 * 4 + ll) * SA + tx * 4];
            v01[ll] = h2f(r.x);
            v23[ll] = h2f(r.y);
        }
        #pragma unroll
        for (int i = 0; i < 4; ++i) {
            uint2 pr = *(const uint2*)&Ah[(ty * 4 + i) * SA + jj4 * 4];
            float2 p01 = h2f(pr.x), p23 = h2f(pr.y);
            oacc[i][0] = fmaf(p23.y, v01[3].x, fmaf(p23.x, v01[2].x, fmaf(p01.y, v01[1].x, fmaf(p01.x, v01[0].x, oacc[i][0]))));
            oacc[i][1] = fmaf(p23.y, v01[3].y, fmaf(p23.x, v01[2].y, fmaf(p01.y, v01[1].y, fmaf(p01.x, v01[0].y, oacc[i][1]))));
            oacc[i][2] = fmaf(p23.y, v23[3].x, fmaf(p23.x, v23[2].x, fmaf(p01.y, v23[1].x, fmaf(p01.x, v23[0].x, oacc[i][2]))));
            oacc[i][3] = fmaf(p23.y, v23[3].y, fmaf(p23.x, v23[2].y, fmaf(p01.y, v23[1].y, fmaf(p01.x, v23[0].y, oacc[i][3]))));
        }
    }

    // emit so rows (coalesced uint2 = 4 f16); rare overflow also atomics out
    #pragma unroll
    for (int i = 0; i < 4; ++i) {
        const int r = ty * 4 + i;
        float o0 = oacc[i][0] * rinv[i];
        float o1 = oacc[i][1] * rinv[i];
        float o2 = oacc[i][2] * rinv[i];
        float o3 = oacc[i][3] * rinv[i];
        unsigned* dst = so + (((size_t)(bh * NC_ + c)) * WSZ_ + r) * (D_ / 2) + tx * 2;
        uint2 pk;
        pk.x = f2h2(o0, o1);
        pk.y = f2h2(o2, o3);
        *(uint2*)dst = pk;
        if (lp[r] >= CAP_) {
            float* ob = out + ((size_t)bh * T_ + qi[r]) * D_ + tx * 4;
            atomicAdd(ob + 0, o0); atomicAdd(ob + 1, o1);
            atomicAdd(ob + 2, o2); atomicAdd(ob + 3, o3);
        }
    }
}

// ---------------------------------------------------------------------------
// K4-so: gather finalize: out[t] = (sum of so rows + overflow)/(n+eps) + aux
// grid: (T/16, BH)  block: 256
// ---------------------------------------------------------------------------
__global__ __launch_bounds__(256)
void k_gather(const unsigned* __restrict__ so, const int* __restrict__ cnt,
              const int* __restrict__ entries, float* __restrict__ out,
              const float* __restrict__ aux)
{
    const int tid = threadIdx.x;
    const int tk  = blockIdx.x * 16 + (tid >> 4);
    const int bh  = blockIdx.y;
    const int d4  = (tid & 15) * 2;     // uint pairs (4 f16)
    const size_t tix = (size_t)bh * T_ + tk;

    const int n = cnt[tix];
    const int m = n < CAP_ ? n : CAP_;
    const int* ep = entries + tix * CAP_;

    float a0 = 0.f, a1 = 0.f, a2 = 0.f, a3 = 0.f;
    for (int j = 0; j < m; ++j) {
        int e = ep[j];
        const unsigned* sp = so + ((size_t)bh * (NC_ * WSZ_) + e) * (D_ / 2) + d4;
        uint2 raw = *(const uint2*)sp;
        float2 f01 = h2f(raw.x), f23 = h2f(raw.y);
        a0 += f01.x; a1 += f01.y; a2 += f23.x; a3 += f23.y;
    }
    float* op = out + tix * D_ + (tid & 15) * 4;
    float4 pr = *(float4*)op;                 // overflow base (normally 0)
    float inv = 1.0f / ((float)n + 1e-5f);
    float4 r;
    r.x = (a0 + pr.x) * inv;
    r.y = (a1 + pr.y) * inv;
    r.z = (a2 + pr.z) * inv;
    r.w = (a3 + pr.w) * inv;
    *(float4*)op = r;

    if (blockIdx.x == 0 && bh == 0 && tid == 0)
        out[(size_t)BH_ * T_ * D_] = aux[0] * 1.4901161193847656e-12f;
}

// ---------------------------------------------------------------------------
// K3/K4 fallback (small-ws): r12 f16 atomic-scatter path
// ---------------------------------------------------------------------------
__global__ __launch_bounds__(256)
void k_attn(const float* __restrict__ q, const float* __restrict__ k,
            const float* __restrict__ v, const int* __restrict__ qidx,
            const int* __restrict__ kidx, float* __restrict__ out,
            float* __restrict__ den)
{
    __shared__ __half Ah[64 * SA];
    __shared__ __half Bh[64 * SA];
    __shared__ int qi[64], ki[64];

    const int tid = threadIdx.x;
    const int c  = blockIdx.x;
    const int bh = blockIdx.y;
    const int* qp = qidx + ((size_t)(bh * NC_ + c)) * WSZ_;
    const int* kp = kidx + ((size_t)(bh * NC_ + c)) * WSZ_;
    if (tid < 64) { qi[tid] = qp[tid]; ki[tid] = kp[tid]; }
    __syncthreads();

    const int grow = tid >> 2, gseg = (tid & 3) * 16;
    {
        const float4* qsrc = (const float4*)(q + ((size_t)bh * T_ + qi[grow]) * D_ + gseg);
        const float4* ksrc = (const float4*)(k + ((size_t)bh * T_ + ki[grow]) * D_ + gseg);
        unsigned* qd = (unsigned*)&Ah[grow * SA + gseg];
        unsigned* kd = (unsigned*)&Bh[grow * SA + gseg];
        #pragma unroll
        for (int j4 = 0; j4 < 4; ++j4) {
            float4 fq = qsrc[j4];
            float4 fk = ksrc[j4];
            qd[j4 * 2 + 0] = f2h2(fq.x, fq.y);
            qd[j4 * 2 + 1] = f2h2(fq.z, fq.w);
            kd[j4 * 2 + 0] = f2h2(fk.x, fk.y);
            kd[j4 * 2 + 1] = f2h2(fk.z, fk.w);
        }
    }
    __syncthreads();

    const int tx = tid & 15;
    const int ty = tid >> 4;

    float sacc[4][4];
    #pragma unroll
    for (int i = 0; i < 4; ++i)
        #pragma unroll
        for (int j = 0; j < 4; ++j) sacc[i][j] = 0.f;

    for (int k4 = 0; k4 < 16; ++k4) {
        float2 qf[8];
        #pragma unroll
        for (int i = 0; i < 4; ++i) {
            uint2 qr = *(const uint2*)&Ah[(ty * 4 + i) * SA + k4 * 4];
            qf[i * 2 + 0] = h2f(qr.x);
            qf[i * 2 + 1] = h2f(qr.y);
        }
        #pragma unroll
        for (int j = 0; j < 4; ++j) {
            uint2 kr = *(const uint2*)&Bh[(tx + j * 16) * SA + k4 * 4];
            float2 k01 = h2f(kr.x), k23 = h2f(kr.y);
            #pragma unroll
            for (int i = 0; i < 4; ++i)
                sacc[i][j] = fmaf(qf[i*2+1].y, k23.y, fmaf(qf[i*2+1].x, k23.x,
                              fmaf(qf[i*2+0].y, k01.y, fmaf(qf[i*2+0].x, k01.x, sacc[i][j]))));
        }
    }
    __syncthreads();

    {
        const float4* vsrc = (const float4*)(v + ((size_t)bh * T_ + ki[grow]) * D_ + gseg);
        unsigned* vd = (unsigned*)&Bh[grow * SA + gseg];
        #pragma unroll
        for (int j4 = 0; j4 < 4; ++j4) {
            float4 f = vsrc[j4];
            vd[j4 * 2 + 0] = f2h2(f.x, f.y);
            vd[j4 * 2 + 1] = f2h2(f.z, f.w);
        }
    }

    float rinv[4];
    #pragma unroll
    for (int i = 0; i < 4; ++i) {
        float m = fmaxf(fmaxf(sacc[i][0], sacc[i][1]), fmaxf(sacc[i][2], sacc[i][3]));
        m = fmaxf(m, __shfl_xor(m, 1));
        m = fmaxf(m, __shfl_xor(m, 2));
        m = fmaxf(m, __shfl_xor(m, 4));
        m = fmaxf(m, __shfl_xor(m, 8));
        float e0 = expf((sacc[i][0] - m) * 0.125f);
        float e1 = expf((sacc[i][1] - m) * 0.125f);
        float e2 = expf((sacc[i][2] - m) * 0.125f);
        float e3 = expf((sacc[i][3] - m) * 0.125f);
        float s = e0 + e1 + e2 + e3;
        s += __shfl_xor(s, 1);
        s += __shfl_xor(s, 2);
        s += __shfl_xor(s, 4);
        s += __shfl_xor(s, 8);
        rinv[i] = 1.0f / s;
        const int rb = (ty * 4 + i) * SA + tx;
        Ah[rb     ] = __float2half(e0);
        Ah[rb + 16] = __float2half(e1);
        Ah[rb + 32] = __float2half(e2);
        Ah[rb + 48] = __float2half(e3);
    }
    __syncthreads();

    float oacc[4][4];
    #pragma unroll
    for (int i = 0; i < 4; ++i)
        #pragma unroll
        for (int j = 0; j < 4; ++j) oacc[i][j] = 0.f;

    for (int jj4 = 0; jj4 < 16; ++jj4) {
        float2 v01[4], v23[4];
        #pragma unroll
        for (int ll = 0; ll < 4; ++ll) {
            uint2 r = *(const uint2*)&Bh[(jj4 * 4 + ll) * SA + tx * 4];
            v01[ll] = h2f(r.x);
            v23[ll] = h2f(r.y);
        }
        #pragma unroll
        for (int i = 0; i < 4; ++i) {
            uint2 pr = *(const uint2*)&Ah[(ty * 4 + i) * SA + jj4 * 4];
            float2 p01 = h2f(pr.x), p23 = h2f(pr.y);
            oacc[i][0] = fmaf(p23.y, v01[3].x, fmaf(p23.x, v01[2].x, fmaf(p01.y, v01[1].x, fmaf(p01.x, v01[0].x, oacc[i][0]))));
            oacc[i][1] = fmaf(p23.y, v01[3].y, fmaf(p23.x, v01[2].y, fmaf(p01.y, v01[1].y, fmaf(p01.x, v01[0].y, oacc[i][1]))));
            oacc[i][2] = fmaf(p23.y, v23[3].x, fmaf(p23.x, v23[2].x, fmaf(p01.y, v23[1].x, fmaf(p01.x, v23[0].x, oacc[i][2]))));
            oacc[i][3] = fmaf(p23.y, v23[3].y, fmaf(p23.x, v23[2].y, fmaf(p01.y, v23[1].y, fmaf(p01.x, v23[0].y, oacc[i][3]))));
        }
    }

    #pragma unroll
    for (int i = 0; i < 4; ++i) {
        const int r = ty * 4 + i;
        float* obase = out + ((size_t)bh * T_ + qi[r]) * D_ + tx * 4;
        #pragma unroll
        for (int j = 0; j < 4; ++j) atomicAdd(obase + j, oacc[i][j] * rinv[i]);
    }
    if (tx == 0) {
        #pragma unroll
        for (int i = 0; i < 4; ++i) atomicAdd(den + (size_t)bh * T_ + qi[ty * 4 + i], 1.0f);
    }
}

__global__ __launch_bounds__(256)
void k_final(float* __restrict__ out, const float* __restrict__ den,
             const float* __restrict__ aux)
{
    size_t gid = (size_t)blockIdx.x * 256 + threadIdx.x;
    float4* o4 = (float4*)out;
    float d = den[gid >> 4] + 1e-5f;
    float4 x = o4[gid];
    x.x = x.x / d; x.y = x.y / d; x.z = x.z / d; x.w = x.w / d;
    o4[gid] = x;
    if (gid == 0) out[(size_t)BH_ * T_ * D_] = aux[0] * 1.4901161193847656e-12f;
}

extern "C" void kernel_launch(void* const* d_in, const int* in_sizes, int n_in,
                              void* d_out, int out_size, void* d_ws, size_t ws_size,
                              hipStream_t stream) {
    const float* q     = (const float*)d_in[0];
    const float* k     = (const float*)d_in[1];
    const float* v     = (const float*)d_in[2];
    const float* means = (const float*)d_in[3];
    float* out = (float*)d_out;
    char*  ws  = (char*)d_ws;
    float* aux    = (float*)(ws + OFF_AUX);
    float* den    = (float*)(ws + OFF_DEN);     // cnt (int) in so-path
    int*   qidx   = (int*)(ws + OFF_QIDX);
    int*   kidx   = (int*)(ws + OFF_KIDX);
    float* meanst = (float*)(ws + OFF_MEANST);
    float* dists  = (float*)(ws + OFF_DISTS);

    hipMemsetAsync(out, 0, (size_t)((size_t)BH_ * T_ * D_ + 1) * 4, stream);
    hipMemsetAsync(ws, 0, (size_t)OFF_QIDX, stream);   // aux + den/cnt

    k_meanst<<<256, 256, 0, stream>>>(means, meanst);

    size_t region = (ws_size > OFF_DISTS) ? ws_size - (size_t)OFF_DISTS : 0;
    size_t per_bh = (size_t)NC_ * T2_ * 4;   // 8 MB
    int nbh = (int)(region / per_bh);
    nbh = nbh < 1 ? 1 : (nbh > BH_ ? BH_ : nbh);
    const bool sopath = region >= (SO_BYTES + ENTRIES_BYTES);

    for (int bh_base = 0; bh_base < BH_; bh_base += nbh) {
        int cur = BH_ - bh_base < nbh ? BH_ - bh_base : nbh;
        k_dists<<<dim3(T2_ / 64, cur), 256, 0, stream>>>(q, k, means, meanst, dists, aux, bh_base);
        k_topk <<<dim3(NC_, cur, 2),    256, 0, stream>>>(dists, qidx, kidx, bh_base);
    }

    if (sopath) {
        unsigned* so = (unsigned*)(ws + OFF_DISTS);
        int* entries = (int*)(ws + OFF_DISTS + SO_BYTES);
        k_attn_w<<<dim3(NC_, BH_), 256, 0, stream>>>(q, k, v, qidx, kidx,
                                                     so, (int*)den, entries, out);
        k_gather<<<dim3(T_ / 16, BH_), 256, 0, stream>>>(so, (int*)den, entries, out, aux);
    } else {
        k_attn<<<dim3(NC_, BH_), 256, 0, stream>>>(q, k, v, qidx, kidx, out, den);
        k_final<<<(BH_ * T_ * D_ / 4 + 255) / 256, 256, 0, stream>>>(out, den, aux);
    }
}

// Round 15
// 844.378 us; speedup vs baseline: 1.5640x; 1.1877x over previous
//
#include <hip/hip_runtime.h>
#include <hip/hip_bf16.h>
#include <hip/hip_fp16.h>
#include <math.h>

#define B_ 8
#define H_ 8
#define T_ 8192
#define D_ 64
#define NC_ 128
#define WSZ_ 64
#define T2_ (2*T_)
#define BH_ (B_*H_)
#define CAP_ 16
#define SA 72   // k_attn LDS row stride in halves
#define SX 65   // k_dists xs stride in floats (odd -> conflict-free)

// workspace layout (bytes)
#define OFF_AUX    0
#define OFF_DEN    4096                              // den (fallback) / cnt (so-path)
#define OFF_QIDX   (OFF_DEN  + BH_*T_*4)
#define OFF_KIDX   (OFF_QIDX + BH_*NC_*WSZ_*4)
#define OFF_MEANST (OFF_KIDX + BH_*NC_*WSZ_*4)
#define OFF_DISTS  (OFF_MEANST + H_*NC_*D_*4)
// dists region: nbh*NC_*T2_*4 bytes; reused after topk as:
//   so      (f16): BH*NC*WSZ*D*2 = 67.1 MB
//   entries (int): BH*T*CAP*4    = 32   MB
#define SO_BYTES      ((size_t)BH_*NC_*WSZ_*D_*2)
#define ENTRIES_BYTES ((size_t)BH_*T_*CAP_*4)

__device__ __forceinline__ float2 h2f(unsigned u) {
    __half2 h = *reinterpret_cast<__half2*>(&u);
    return __half22float2(h);
}
__device__ __forceinline__ unsigned f2h2(float a, float b) {
    __half2 h = __float22half2_rn(make_float2(a, b));
    return *reinterpret_cast<unsigned*>(&h);
}

// ---------------------------------------------------------------------------
// K0: transpose means [h][c][d] -> meanst [h][d][c]
// ---------------------------------------------------------------------------
__global__ __launch_bounds__(256)
void k_meanst(const float* __restrict__ means, float* __restrict__ meanst)
{
    int gid = blockIdx.x * 256 + threadIdx.x;
    int h = gid >> 13;
    int rem = gid & 8191;
    int d = rem >> 7;
    int c = rem & 127;
    meanst[gid] = means[((h << 7) | c) * 64 + d];
}

// ---------------------------------------------------------------------------
// K1 v8: scalar-pipe means. lane = token (64), wave = 32-cluster slab ->
// means row is wave-uniform (readfirstlane) -> s_load via scalar cache;
// the d-loop has ZERO vector-memory ops except one ds_read_b32. acc[32]/lane,
// single ascending-d fmaf chain per (token,cluster) -> bitwise-identical
// dists; argmax tie-break = lowest cluster id (ascending scan, strict >).
// grid: (T2/64, nbh)  block: 256.  LDS ~19.4 KB -> 8 blocks/CU.
// ---------------------------------------------------------------------------
__global__ __launch_bounds__(256)
void k_dists(const float* __restrict__ q, const float* __restrict__ k,
             const float* __restrict__ means, const float* __restrict__ meanst,
             float* __restrict__ dists, float* __restrict__ aux, int bh_base)
{
    __shared__ float xs[64 * SX];    // [d][token(64)], stride 65
    __shared__ float bvs[4][64];
    __shared__ int   bis[4][64];
    __shared__ int   bcs[64];
    __shared__ float ar[4];

    const int tid = threadIdx.x;
    const int bhl = blockIdx.y;
    const int bh  = bh_base + bhl;
    const int h   = bh % H_;
    const int t0  = blockIdx.x * 64;
    const int lane = tid & 63;
    const int w    = tid >> 6;

    // ---- phase 1: load 64 token rows (nt), normalize, store transposed
    for (int it = 0; it < 16; ++it) {
        int tl = it * 4 + w;
        int gt = t0 + tl;
        const float* src = (gt < T_)
            ? (q + ((size_t)bh * T_ + gt) * D_)
            : (k + ((size_t)bh * T_ + (gt - T_)) * D_);
        float vv = __builtin_nontemporal_load(src + lane);
        float s = vv * vv;
        #pragma unroll
        for (int off = 32; off > 0; off >>= 1) s += __shfl_xor(s, off);
        float norm = fmaxf(sqrtf(s), 1e-12f);
        xs[lane * SX + tl] = vv / norm;
    }
    __syncthreads();

    // ---- phase 2: lane's token x wave's 32 clusters, means via scalar pipe
    const int wu = __builtin_amdgcn_readfirstlane(w);
    const float* mw = meanst + (size_t)h * (64 * 128) + wu * 32;

    float acc[32];
    #pragma unroll
    for (int j = 0; j < 32; ++j) acc[j] = 0.f;

    #pragma unroll 2
    for (int d = 0; d < 64; ++d) {
        float xv = xs[d * SX + lane];
        const float* mrow = mw + d * 128;
        #pragma unroll
        for (int j = 0; j < 32; ++j)
            acc[j] = fmaf(xv, mrow[j], acc[j]);
    }

    // ---- phase 3: transposed global store (per cluster row, 64 lanes coalesced)
    {
        float* gb = dists + ((size_t)(bhl * NC_ + wu * 32)) * T2_ + t0 + lane;
        #pragma unroll
        for (int j = 0; j < 32; ++j)
            gb[(size_t)j * T2_] = acc[j];
    }

    // ---- phase 4: argmax (ascending j keeps lowest id; cross-wave ascending)
    {
        float bv = acc[0]; int bj = 0;
        #pragma unroll
        for (int j = 1; j < 32; ++j)
            if (acc[j] > bv) { bv = acc[j]; bj = j; }
        bvs[w][lane] = bv;
        bis[w][lane] = wu * 32 + bj;
    }
    __syncthreads();
    if (tid < 64) {
        float b = bvs[0][tid]; int bi = bis[0][tid];
        #pragma unroll
        for (int ww = 1; ww < 4; ++ww) {
            float ov = bvs[ww][tid];
            if (ov > b) { b = ov; bi = bis[ww][tid]; }
        }
        bcs[tid] = bi;
    }
    __syncthreads();

    // ---- phase 5: aux = sum (xn - mean_best)^2
    float part = 0.f;
    for (int it = 0; it < 16; ++it) {
        int tl = it * 4 + w;
        int cb = bcs[tl];
        const float* mr = means + ((size_t)(h * NC_ + cb)) * 64;
        float df = xs[lane * SX + tl] - mr[lane];
        part = fmaf(df, df, part);
    }
    #pragma unroll
    for (int off = 32; off > 0; off >>= 1) part += __shfl_xor(part, off);
    if (lane == 0) ar[w] = part;
    __syncthreads();
    if (tid == 0) atomicAdd(aux, ar[0] + ar[1] + ar[2] + ar[3]);
}

// ---------------------------------------------------------------------------
// K2: top-64 of 8192 — register-resident, 12-bit histogram, parallel
// suffix-scan threshold, exact candidate rank.  (unchanged, passing)
// ---------------------------------------------------------------------------
__device__ __forceinline__ unsigned flip_f32(float f) {
    unsigned bits = __float_as_uint(f);
    return (bits & 0x80000000u) ? ~bits : (bits | 0x80000000u);
}

__global__ __launch_bounds__(256)
void k_topk(const float* __restrict__ dists, int* __restrict__ qidx,
            int* __restrict__ kidx, int bh_base)
{
    __shared__ unsigned hist[4096];
    __shared__ unsigned sfx[256];
    __shared__ unsigned wtot[4];
    __shared__ unsigned cand_u[768];
    __shared__ int      cand_i[768];
    __shared__ int sh[6];

    const int tid   = threadIdx.x;
    const int c     = blockIdx.x;
    const int bhl   = blockIdx.y;
    const int which = blockIdx.z;
    const float* row = dists + ((size_t)(bhl * NC_ + c)) * T2_ + (size_t)which * T_;
    int* outp = (which ? kidx : qidx) + ((size_t)((bh_base + bhl) * NC_ + c)) * WSZ_;

    unsigned u[32];
    {
        const float4* r4 = (const float4*)row;
        #pragma unroll
        for (int it = 0; it < 8; ++it) {
            float4 f = r4[it * 256 + tid];
            u[it * 4 + 0] = flip_f32(f.x);
            u[it * 4 + 1] = flip_f32(f.y);
            u[it * 4 + 2] = flip_f32(f.z);
            u[it * 4 + 3] = flip_f32(f.w);
        }
    }
    for (int i = tid; i < 4096; i += 256) hist[i] = 0;
    if (tid < 6) sh[tid] = (tid < 2) ? -1 : 0;
    __syncthreads();

    #pragma unroll
    for (int j = 0; j < 32; ++j) atomicAdd(&hist[u[j] >> 20], 1u);
    __syncthreads();

    unsigned gs = 0;
    #pragma unroll
    for (int j = 0; j < 16; ++j) gs += hist[tid * 16 + j];

    const int l = tid & 63, w = tid >> 6;
    unsigned sv = gs;
    #pragma unroll
    for (int off = 1; off < 64; off <<= 1) {
        unsigned up = __shfl_down(sv, off);
        if (l + off < 64) sv += up;
    }
    if (l == 0) wtot[w] = sv;
    __syncthreads();
    unsigned hi = 0;
    for (int ww = w + 1; ww < 4; ++ww) hi += wtot[ww];
    unsigned suffix = sv + hi;
    sfx[tid] = suffix;
    if (suffix >= WSZ_) atomicMax(&sh[0], tid);
    __syncthreads();
    const int g1 = sh[0];
    const unsigned above_groups = (g1 < 255) ? sfx[g1 + 1] : 0u;

    if (tid < 16) {
        unsigned bs = above_groups;
        for (int j = 15; j >= tid; --j) bs += hist[g1 * 16 + j];
        if (bs >= WSZ_) atomicMax(&sh[1], g1 * 16 + tid);
    }
    __syncthreads();
    const int b1 = sh[1];
    if (tid == 0) {
        unsigned gt = above_groups;
        for (int j = b1 + 1; j <= g1 * 16 + 15; ++j) gt += hist[j];
        sh[4] = WSZ_ - (int)gt;
    }
    __syncthreads();
    const int kk = sh[4];

    #pragma unroll
    for (int j = 0; j < 32; ++j) {
        int bin = (int)(u[j] >> 20);
        int idx = (j >> 2) * 1024 + tid * 4 + (j & 3);
        if (bin > b1) {
            int p = atomicAdd(&sh[2], 1);
            outp[p] = idx;
        } else if (bin == b1) {
            int p = atomicAdd(&sh[3], 1);
            if (p < 768) { cand_u[p] = u[j]; cand_i[p] = idx; }
        }
    }
    __syncthreads();
    const int G = sh[2];
    const int C = sh[3];

    if (C <= 768) {
        for (int j = tid; j < C; j += 256) {
            unsigned uj = cand_u[j]; int ij = cand_i[j];
            int rank = 0;
            for (int ll = 0; ll < C; ++ll) {
                unsigned ul = cand_u[ll];
                rank += (int)((ul > uj) || (ul == uj && cand_i[ll] < ij));
            }
            if (rank < kk) outp[G + rank] = ij;
        }
        return;
    }

    // fallback: full 4-level radix re-reading global
    unsigned prefix = 0, mask = 0;
    int need = WSZ_;
    for (int shift = 24; shift >= 0; shift -= 8) {
        if (tid < 256) hist[tid] = 0;
        __syncthreads();
        for (int it = 0; it < 32; ++it) {
            unsigned uu = flip_f32(row[it * 256 + tid]);
            if ((uu & mask) == prefix) atomicAdd(&hist[(uu >> shift) & 255u], 1u);
        }
        __syncthreads();
        if (tid == 0) {
            int b = 255;
            int k2 = need;
            while (b > 0) {
                int cnt = (int)hist[b];
                if (k2 - cnt <= 0) break;
                k2 -= cnt; --b;
            }
            sh[0] = k2; sh[1] = b;
        }
        __syncthreads();
        need = sh[0];
        prefix |= ((unsigned)sh[1]) << shift;
        mask   |= 0xFFu << shift;
        __syncthreads();
    }
    if (tid == 0) { sh[2] = 0; sh[3] = 0; }
    __syncthreads();
    const unsigned thr = prefix;
    for (int it = 0; it < 32; ++it) {
        int i = it * 256 + tid;
        unsigned uu = flip_f32(row[i]);
        if (uu > thr) {
            int p = atomicAdd(&sh[2], 1);
            outp[p] = i;
        } else if (uu == thr) {
            int p = atomicAdd(&sh[3], 1);
            if (p < 768) cand_i[p] = i;
        }
    }
    __syncthreads();
    if (tid == 0) {
        int base = sh[2];
        int E = sh[3] < 768 ? sh[3] : 768;
        for (int n = 0; n < need; ++n) {
            int mi = 0x7fffffff, mj = 0;
            for (int j = 0; j < E; ++j) {
                int vv = cand_i[j];
                if (vv < mi) { mi = vv; mj = j; }
            }
            cand_i[mj] = 0x7fffffff;
            outp[base + n] = mi;
        }
    }
}

// ---------------------------------------------------------------------------
// K3-so v4 (r13/r14, passing): f16 body + so/entries gather epilogue.
// grid: (NC, BH)  block: 256
// ---------------------------------------------------------------------------
__global__ __launch_bounds__(256)
void k_attn_w(const float* __restrict__ q, const float* __restrict__ k,
              const float* __restrict__ v, const int* __restrict__ qidx,
              const int* __restrict__ kidx, unsigned* __restrict__ so,
              int* __restrict__ cnt, int* __restrict__ entries,
              float* __restrict__ out)
{
    __shared__ __half Ah[64 * SA];   // Q (f16), then P (f16)
    __shared__ __half Bh[64 * SA];   // K (f16), then V (f16)
    __shared__ int qi[64], ki[64], lp[64];

    const int tid = threadIdx.x;
    const int c  = blockIdx.x;
    const int bh = blockIdx.y;
    const int* qp = qidx + ((size_t)(bh * NC_ + c)) * WSZ_;
    const int* kp = kidx + ((size_t)(bh * NC_ + c)) * WSZ_;
    if (tid < 64) { qi[tid] = qp[tid]; ki[tid] = kp[tid]; }
    __syncthreads();

    const int grow = tid >> 2, gseg = (tid & 3) * 16;
    {
        const float4* qsrc = (const float4*)(q + ((size_t)bh * T_ + qi[grow]) * D_ + gseg);
        const float4* ksrc = (const float4*)(k + ((size_t)bh * T_ + ki[grow]) * D_ + gseg);
        unsigned* qd = (unsigned*)&Ah[grow * SA + gseg];
        unsigned* kd = (unsigned*)&Bh[grow * SA + gseg];
        #pragma unroll
        for (int j4 = 0; j4 < 4; ++j4) {
            float4 fq = qsrc[j4];
            float4 fk = ksrc[j4];
            qd[j4 * 2 + 0] = f2h2(fq.x, fq.y);
            qd[j4 * 2 + 1] = f2h2(fq.z, fq.w);
            kd[j4 * 2 + 0] = f2h2(fk.x, fk.y);
            kd[j4 * 2 + 1] = f2h2(fk.z, fk.w);
        }
    }
    __syncthreads();

    const int tx = tid & 15;
    const int ty = tid >> 4;

    float sacc[4][4];
    #pragma unroll
    for (int i = 0; i < 4; ++i)
        #pragma unroll
        for (int j = 0; j < 4; ++j) sacc[i][j] = 0.f;

    for (int k4 = 0; k4 < 16; ++k4) {
        float2 qf[8];
        #pragma unroll
        for (int i = 0; i < 4; ++i) {
            uint2 qr = *(const uint2*)&Ah[(ty * 4 + i) * SA + k4 * 4];
            qf[i * 2 + 0] = h2f(qr.x);
            qf[i * 2 + 1] = h2f(qr.y);
        }
        #pragma unroll
        for (int j = 0; j < 4; ++j) {
            uint2 kr = *(const uint2*)&Bh[(tx + j * 16) * SA + k4 * 4];
            float2 k01 = h2f(kr.x), k23 = h2f(kr.y);
            #pragma unroll
            for (int i = 0; i < 4; ++i)
                sacc[i][j] = fmaf(qf[i*2+1].y, k23.y, fmaf(qf[i*2+1].x, k23.x,
                              fmaf(qf[i*2+0].y, k01.y, fmaf(qf[i*2+0].x, k01.x, sacc[i][j]))));
        }
    }
    __syncthreads();   // K reads done -> Bh reusable

    // stage V (f32 -> f16)
    {
        const float4* vsrc = (const float4*)(v + ((size_t)bh * T_ + ki[grow]) * D_ + gseg);
        unsigned* vd = (unsigned*)&Bh[grow * SA + gseg];
        #pragma unroll
        for (int j4 = 0; j4 < 4; ++j4) {
            float4 f = vsrc[j4];
            vd[j4 * 2 + 0] = f2h2(f.x, f.y);
            vd[j4 * 2 + 1] = f2h2(f.z, f.w);
        }
    }

    // registration (overlaps with softmax)
    if (tx == 0) {
        #pragma unroll
        for (int i = 0; i < 4; ++i) {
            int r = ty * 4 + i;
            int t = qi[r];
            int p = atomicAdd(&cnt[(size_t)bh * T_ + t], 1);
            if (p < CAP_) entries[((size_t)bh * T_ + t) * CAP_ + p] = c * WSZ_ + r;
            lp[r] = p;
        }
    }

    float rinv[4];
    #pragma unroll
    for (int i = 0; i < 4; ++i) {
        float m = fmaxf(fmaxf(sacc[i][0], sacc[i][1]), fmaxf(sacc[i][2], sacc[i][3]));
        m = fmaxf(m, __shfl_xor(m, 1));
        m = fmaxf(m, __shfl_xor(m, 2));
        m = fmaxf(m, __shfl_xor(m, 4));
        m = fmaxf(m, __shfl_xor(m, 8));
        float e0 = expf((sacc[i][0] - m) * 0.125f);
        float e1 = expf((sacc[i][1] - m) * 0.125f);
        float e2 = expf((sacc[i][2] - m) * 0.125f);
        float e3 = expf((sacc[i][3] - m) * 0.125f);
        float s = e0 + e1 + e2 + e3;
        s += __shfl_xor(s, 1);
        s += __shfl_xor(s, 2);
        s += __shfl_xor(s, 4);
        s += __shfl_xor(s, 8);
        rinv[i] = 1.0f / s;
        const int rb = (ty * 4 + i) * SA + tx;
        Ah[rb     ] = __float2half(e0);
        Ah[rb + 16] = __float2half(e1);
        Ah[rb + 32] = __float2half(e2);
        Ah[rb + 48] = __float2half(e3);
    }
    __syncthreads();   // P stored, V staged, lp valid

    float oacc[4][4];
    #pragma unroll
    for (int i = 0; i < 4; ++i)
        #pragma unroll
        for (int j = 0; j < 4; ++j) oacc[i][j] = 0.f;

    for (int jj4 = 0; jj4 < 16; ++jj4) {
        float2 v01[4], v23[4];
        #pragma unroll
        for (int ll = 0; ll < 4; ++ll) {
            uint2 r = *(const uint2*)&Bh[(jj4 * 4 + ll) * SA + tx * 4];
            v01[ll] = h2f(r.x);
            v23[ll] = h2f(r.y);
        }
        #pragma unroll
        for (int i = 0; i < 4; ++i) {
            uint2 pr = *(const uint2*)&Ah[(ty * 4 + i) * SA + jj4 * 4];
            float2 p01 = h2f(pr.x), p23 = h2f(pr.y);
            oacc[i][0] = fmaf(p23.y, v01[3].x, fmaf(p23.x, v01[2].x, fmaf(p01.y, v01[1].x, fmaf(p01.x, v01[0].x, oacc[i][0]))));
            oacc[i][1] = fmaf(p23.y, v01[3].y, fmaf(p23.x, v01[2].y, fmaf(p01.y, v01[1].y, fmaf(p01.x, v01[0].y, oacc[i][1]))));
            oacc[i][2] = fmaf(p23.y, v23[3].x, fmaf(p23.x, v23[2].x, fmaf(p01.y, v23[1].x, fmaf(p01.x, v23[0].x, oacc[i][2]))));
            oacc[i][3] = fmaf(p23.y, v23[3].y, fmaf(p23.x, v23[2].y, fmaf(p01.y, v23[1].y, fmaf(p01.x, v23[0].y, oacc[i][3]))));
        }
    }

    // emit so rows (coalesced uint2 = 4 f16); rare overflow also atomics out
    #pragma unroll
    for (int i = 0; i < 4; ++i) {
        const int r = ty * 4 + i;
        float o0 = oacc[i][0] * rinv[i];
        float o1 = oacc[i][1] * rinv[i];
        float o2 = oacc[i][2] * rinv[i];
        float o3 = oacc[i][3] * rinv[i];
        unsigned* dst = so + (((size_t)(bh * NC_ + c)) * WSZ_ + r) * (D_ / 2) + tx * 2;
        uint2 pk;
        pk.x = f2h2(o0, o1);
        pk.y = f2h2(o2, o3);
        *(uint2*)dst = pk;
        if (lp[r] >= CAP_) {
            float* ob = out + ((size_t)bh * T_ + qi[r]) * D_ + tx * 4;
            atomicAdd(ob + 0, o0); atomicAdd(ob + 1, o1);
            atomicAdd(ob + 2, o2); atomicAdd(ob + 3, o3);
        }
    }
}

// ---------------------------------------------------------------------------
// K4-so: gather finalize: out[t] = (sum of so rows + overflow)/(n+eps) + aux
// grid: (T/16, BH)  block: 256
// ---------------------------------------------------------------------------
__global__ __launch_bounds__(256)
void k_gather(const unsigned* __restrict__ so, const int* __restrict__ cnt,
              const int* __restrict__ entries, float* __restrict__ out,
              const float* __restrict__ aux)
{
    const int tid = threadIdx.x;
    const int tk  = blockIdx.x * 16 + (tid >> 4);
    const int bh  = blockIdx.y;
    const int d4  = (tid & 15) * 2;     // uint pairs (4 f16)
    const size_t tix = (size_t)bh * T_ + tk;

    const int n = cnt[tix];
    const int m = n < CAP_ ? n : CAP_;
    const int* ep = entries + tix * CAP_;

    float a0 = 0.f, a1 = 0.f, a2 = 0.f, a3 = 0.f;
    for (int j = 0; j < m; ++j) {
        int e = ep[j];
        const unsigned* sp = so + ((size_t)bh * (NC_ * WSZ_) + e) * (D_ / 2) + d4;
        uint2 raw = *(const uint2*)sp;
        float2 f01 = h2f(raw.x), f23 = h2f(raw.y);
        a0 += f01.x; a1 += f01.y; a2 += f23.x; a3 += f23.y;
    }
    float* op = out + tix * D_ + (tid & 15) * 4;
    float4 pr = *(float4*)op;                 // overflow base (normally 0)
    float inv = 1.0f / ((float)n + 1e-5f);
    float4 r;
    r.x = (a0 + pr.x) * inv;
    r.y = (a1 + pr.y) * inv;
    r.z = (a2 + pr.z) * inv;
    r.w = (a3 + pr.w) * inv;
    *(float4*)op = r;

    if (blockIdx.x == 0 && bh == 0 && tid == 0)
        out[(size_t)BH_ * T_ * D_] = aux[0] * 1.4901161193847656e-12f;
}

// ---------------------------------------------------------------------------
// K3/K4 fallback (small-ws): r12 f16 atomic-scatter path
// ---------------------------------------------------------------------------
__global__ __launch_bounds__(256)
void k_attn(const float* __restrict__ q, const float* __restrict__ k,
            const float* __restrict__ v, const int* __restrict__ qidx,
            const int* __restrict__ kidx, float* __restrict__ out,
            float* __restrict__ den)
{
    __shared__ __half Ah[64 * SA];
    __shared__ __half Bh[64 * SA];
    __shared__ int qi[64], ki[64];

    const int tid = threadIdx.x;
    const int c  = blockIdx.x;
    const int bh = blockIdx.y;
    const int* qp = qidx + ((size_t)(bh * NC_ + c)) * WSZ_;
    const int* kp = kidx + ((size_t)(bh * NC_ + c)) * WSZ_;
    if (tid < 64) { qi[tid] = qp[tid]; ki[tid] = kp[tid]; }
    __syncthreads();

    const int grow = tid >> 2, gseg = (tid & 3) * 16;
    {
        const float4* qsrc = (const float4*)(q + ((size_t)bh * T_ + qi[grow]) * D_ + gseg);
        const float4* ksrc = (const float4*)(k + ((size_t)bh * T_ + ki[grow]) * D_ + gseg);
        unsigned* qd = (unsigned*)&Ah[grow * SA + gseg];
        unsigned* kd = (unsigned*)&Bh[grow * SA + gseg];
        #pragma unroll
        for (int j4 = 0; j4 < 4; ++j4) {
            float4 fq = qsrc[j4];
            float4 fk = ksrc[j4];
            qd[j4 * 2 + 0] = f2h2(fq.x, fq.y);
            qd[j4 * 2 + 1] = f2h2(fq.z, fq.w);
            kd[j4 * 2 + 0] = f2h2(fk.x, fk.y);
            kd[j4 * 2 + 1] = f2h2(fk.z, fk.w);
        }
    }
    __syncthreads();

    const int tx = tid & 15;
    const int ty = tid >> 4;

    float sacc[4][4];
    #pragma unroll
    for (int i = 0; i < 4; ++i)
        #pragma unroll
        for (int j = 0; j < 4; ++j) sacc[i][j] = 0.f;

    for (int k4 = 0; k4 < 16; ++k4) {
        float2 qf[8];
        #pragma unroll
        for (int i = 0; i < 4; ++i) {
            uint2 qr = *(const uint2*)&Ah[(ty * 4 + i) * SA + k4 * 4];
            qf[i * 2 + 0] = h2f(qr.x);
            qf[i * 2 + 1] = h2f(qr.y);
        }
        #pragma unroll
        for (int j = 0; j < 4; ++j) {
            uint2 kr = *(const uint2*)&Bh[(tx + j * 16) * SA + k4 * 4];
            float2 k01 = h2f(kr.x), k23 = h2f(kr.y);
            #pragma unroll
            for (int i = 0; i < 4; ++i)
                sacc[i][j] = fmaf(qf[i*2+1].y, k23.y, fmaf(qf[i*2+1].x, k23.x,
                              fmaf(qf[i*2+0].y, k01.y, fmaf(qf[i*2+0].x, k01.x, sacc[i][j]))));
        }
    }
    __syncthreads();

    {
        const float4* vsrc = (const float4*)(v + ((size_t)bh * T_ + ki[grow]) * D_ + gseg);
        unsigned* vd = (unsigned*)&Bh[grow * SA + gseg];
        #pragma unroll
        for (int j4 = 0; j4 < 4; ++j4) {
            float4 f = vsrc[j4];
            vd[j4 * 2 + 0] = f2h2(f.x, f.y);
            vd[j4 * 2 + 1] = f2h2(f.z, f.w);
        }
    }

    float rinv[4];
    #pragma unroll
    for (int i = 0; i < 4; ++i) {
        float m = fmaxf(fmaxf(sacc[i][0], sacc[i][1]), fmaxf(sacc[i][2], sacc[i][3]));
        m = fmaxf(m, __shfl_xor(m, 1));
        m = fmaxf(m, __shfl_xor(m, 2));
        m = fmaxf(m, __shfl_xor(m, 4));
        m = fmaxf(m, __shfl_xor(m, 8));
        float e0 = expf((sacc[i][0] - m) * 0.125f);
        float e1 = expf((sacc[i][1] - m) * 0.125f);
        float e2 = expf((sacc[i][2] - m) * 0.125f);
        float e3 = expf((sacc[i][3] - m) * 0.125f);
        float s = e0 + e1 + e2 + e3;
        s += __shfl_xor(s, 1);
        s += __shfl_xor(s, 2);
        s += __shfl_xor(s, 4);
        s += __shfl_xor(s, 8);
        rinv[i] = 1.0f / s;
        const int rb = (ty * 4 + i) * SA + tx;
        Ah[rb     ] = __float2half(e0);
        Ah[rb + 16] = __float2half(e1);
        Ah[rb + 32] = __float2half(e2);
        Ah[rb + 48] = __float2half(e3);
    }
    __syncthreads();

    float oacc[4][4];
    #pragma unroll
    for (int i = 0; i < 4; ++i)
        #pragma unroll
        for (int j = 0; j < 4; ++j) oacc[i][j] = 0.f;

    for (int jj4 = 0; jj4 < 16; ++jj4) {
        float2 v01[4], v23[4];
        #pragma unroll
        for (int ll = 0; ll < 4; ++ll) {
            uint2 r = *(const uint2*)&Bh[(jj4 * 4 + ll) * SA + tx * 4];
            v01[ll] = h2f(r.x);
            v23[ll] = h2f(r.y);
        }
        #pragma unroll
        for (int i = 0; i < 4; ++i) {
            uint2 pr = *(const uint2*)&Ah[(ty * 4 + i) * SA + jj4 * 4];
            float2 p01 = h2f(pr.x), p23 = h2f(pr.y);
            oacc[i][0] = fmaf(p23.y, v01[3].x, fmaf(p23.x, v01[2].x, fmaf(p01.y, v01[1].x, fmaf(p01.x, v01[0].x, oacc[i][0]))));
            oacc[i][1] = fmaf(p23.y, v01[3].y, fmaf(p23.x, v01[2].y, fmaf(p01.y, v01[1].y, fmaf(p01.x, v01[0].y, oacc[i][1]))));
            oacc[i][2] = fmaf(p23.y, v23[3].x, fmaf(p23.x, v23[2].x, fmaf(p01.y, v23[1].x, fmaf(p01.x, v23[0].x, oacc[i][2]))));
            oacc[i][3] = fmaf(p23.y, v23[3].y, fmaf(p23.x, v23[2].y, fmaf(p01.y, v23[1].y, fmaf(p01.x, v23[0].y, oacc[i][3]))));
        }
    }

    #pragma unroll
    for (int i = 0; i < 4; ++i) {
        const int r = ty * 4 + i;
        float* obase = out + ((size_t)bh * T_ + qi[r]) * D_ + tx * 4;
        #pragma unroll
        for (int j = 0; j < 4; ++j) atomicAdd(obase + j, oacc[i][j] * rinv[i]);
    }
    if (tx == 0) {
        #pragma unroll
        for (int i = 0; i < 4; ++i) atomicAdd(den + (size_t)bh * T_ + qi[ty * 4 + i], 1.0f);
    }
}

__global__ __launch_bounds__(256)
void k_final(float* __restrict__ out, const float* __restrict__ den,
             const float* __restrict__ aux)
{
    size_t gid = (size_t)blockIdx.x * 256 + threadIdx.x;
    float4* o4 = (float4*)out;
    float d = den[gid >> 4] + 1e-5f;
    float4 x = o4[gid];
    x.x = x.x / d; x.y = x.y / d; x.z = x.z / d; x.w = x.w / d;
    o4[gid] = x;
    if (gid == 0) out[(size_t)BH_ * T_ * D_] = aux[0] * 1.4901161193847656e-12f;
}

extern "C" void kernel_launch(void* const* d_in, const int* in_sizes, int n_in,
                              void* d_out, int out_size, void* d_ws, size_t ws_size,
                              hipStream_t stream) {
    const float* q     = (const float*)d_in[0];
    const float* k     = (const float*)d_in[1];
    const float* v     = (const float*)d_in[2];
    const float* means = (const float*)d_in[3];
    float* out = (float*)d_out;
    char*  ws  = (char*)d_ws;
    float* aux    = (float*)(ws + OFF_AUX);
    float* den    = (float*)(ws + OFF_DEN);     // cnt (int) in so-path
    int*   qidx   = (int*)(ws + OFF_QIDX);
    int*   kidx   = (int*)(ws + OFF_KIDX);
    float* meanst = (float*)(ws + OFF_MEANST);
    float* dists  = (float*)(ws + OFF_DISTS);

    hipMemsetAsync(out, 0, (size_t)((size_t)BH_ * T_ * D_ + 1) * 4, stream);
    hipMemsetAsync(ws, 0, (size_t)OFF_QIDX, stream);   // aux + den/cnt

    k_meanst<<<256, 256, 0, stream>>>(means, meanst);

    size_t region = (ws_size > OFF_DISTS) ? ws_size - (size_t)OFF_DISTS : 0;
    size_t per_bh = (size_t)NC_ * T2_ * 4;   // 8 MB
    int nbh = (int)(region / per_bh);
    nbh = nbh < 1 ? 1 : (nbh > BH_ ? BH_ : nbh);
    const bool sopath = region >= (SO_BYTES + ENTRIES_BYTES);

    for (int bh_base = 0; bh_base < BH_; bh_base += nbh) {
        int cur = BH_ - bh_base < nbh ? BH_ - bh_base : nbh;
        k_dists<<<dim3(T2_ / 64, cur), 256, 0, stream>>>(q, k, means, meanst, dists, aux, bh_base);
        k_topk <<<dim3(NC_, cur, 2),    256, 0, stream>>>(dists, qidx, kidx, bh_base);
    }

    if (sopath) {
        unsigned* so = (unsigned*)(ws + OFF_DISTS);
        int* entries = (int*)(ws + OFF_DISTS + SO_BYTES);
        k_attn_w<<<dim3(NC_, BH_), 256, 0, stream>>>(q, k, v, qidx, kidx,
                                                     so, (int*)den, entries, out);
        k_gather<<<dim3(T_ / 16, BH_), 256, 0, stream>>>(so, (int*)den, entries, out, aux);
    } else {
        k_attn<<<dim3(NC_, BH_), 256, 0, stream>>>(q, k, v, qidx, kidx, out, den);
        k_final<<<(BH_ * T_ * D_ / 4 + 255) / 256, 256, 0, stream>>>(out, den, aux);
    }
}